// Round 3
// baseline (1603.656 us; speedup 1.0000x reference)
//
#include <hip/hip_runtime.h>

#define HDIM 108
constexpr int G_GRAPHS = 128;

// ---------------- CSR build ----------------

__global__ __launch_bounds__(256) void k_deg(const int* __restrict__ dst, int* __restrict__ deg, int E) {
  int e = blockIdx.x * 256 + threadIdx.x;
  if (e < E) atomicAdd(&deg[dst[e]], 1);
}

__global__ __launch_bounds__(256) void k_blocksum(const int* __restrict__ deg, int* __restrict__ bsum, int N) {
  __shared__ int s[256];
  int t = threadIdx.x;
  int i = blockIdx.x * 256 + t;
  s[t] = (i < N) ? deg[i] : 0;
  __syncthreads();
  for (int off = 128; off > 0; off >>= 1) {
    if (t < off) s[t] += s[t + off];
    __syncthreads();
  }
  if (t == 0) bsum[blockIdx.x] = s[0];
}

__global__ __launch_bounds__(512) void k_scan_bsum(const int* __restrict__ bsum, int* __restrict__ boff, int nb) {
  __shared__ int s[512];
  int t = threadIdx.x;
  int own = (t < nb) ? bsum[t] : 0;
  s[t] = own;
  __syncthreads();
  for (int off = 1; off < 512; off <<= 1) {
    int x = (t >= off) ? s[t - off] : 0;
    __syncthreads();
    s[t] += x;
    __syncthreads();
  }
  if (t < nb) boff[t] = s[t] - own;  // exclusive
}

__global__ __launch_bounds__(256) void k_scan_final(const int* __restrict__ deg, const int* __restrict__ boff,
                                                    int* __restrict__ rowStart, int* __restrict__ cursor, int N) {
  __shared__ int s[256];
  int t = threadIdx.x;
  int i = blockIdx.x * 256 + t;
  int own = (i < N) ? deg[i] : 0;
  s[t] = own;
  __syncthreads();
  for (int off = 1; off < 256; off <<= 1) {
    int x = (t >= off) ? s[t - off] : 0;
    __syncthreads();
    s[t] += x;
    __syncthreads();
  }
  if (i < N) {
    int rs = boff[blockIdx.x] + s[t] - own;
    rowStart[i] = rs;
    cursor[i] = rs;
  }
}

__global__ __launch_bounds__(256) void k_fill(const int* __restrict__ src, const int* __restrict__ dst,
                                              int* __restrict__ cursor, int* __restrict__ csr, int E) {
  int e = blockIdx.x * 256 + threadIdx.x;
  if (e < E) {
    int pos = atomicAdd(&cursor[dst[e]], 1);
    csr[pos] = src[e];  // store source node id directly
  }
}

// ---------------- GEMM: out[N,108] = A[N,K] @ W[K,108] (+bias, act) ----------------
// Block 256 threads, tile 128 nodes x 108 cols.
// Thread mapping: co = tid&31 (float4 col group; 27 active, rest clamped), nr = tid>>5.
// Each thread: 16 nodes (nr + m*8) x 4 consecutive cols -> float4 epilogue I/O.
// K staged in LDS chunks of KC (36 or 32), A stride KC+4 floats (16B-aligned pad).
// MODE 0: +bias. MODE 1: +bias, ReLU. MODE 2: +bias -> row L2 norm -> ReLU -> residual (in-place h).

template <int K, int KC, int MODE>
__global__ __launch_bounds__(256, 4) void k_mm(const float* A, const float* __restrict__ A2,
                                               const float* __restrict__ Wg, const float* __restrict__ bias,
                                               float* out, int N) {
  constexpr int NCH = K / KC;            // chunks
  constexpr int F4C = KC / 4;            // float4 per row chunk
  constexpr int AST = KC + 4;            // As stride in floats (16B aligned, bank-skewed)
  constexpr int RowF4 = (K == 64) ? 16 : 27;  // source row length in float4 (per source array)
  __shared__ float As[128 * AST];
  __shared__ float Ws[KC * 112 + 16];    // +16 slack for clamped-lane b128 reads

  const int tid = threadIdx.x;
  const int co = tid & 31;
  const int coc = (co < 27) ? co : 26;   // clamp idle lanes (duplicate last group)
  const int nr = tid >> 5;               // 0..7
  const int n0 = blockIdx.x * 128;

  float acc[16][4];
#pragma unroll
  for (int m = 0; m < 16; m++)
#pragma unroll
    for (int j = 0; j < 4; j++) acc[m][j] = 0.f;

#pragma unroll 1
  for (int kc = 0; kc < NCH; kc++) {
    // ---- stage A chunk: 128 rows x F4C float4 ----
    const float* srcA = (K == 216 && kc >= 3) ? A2 : A;
    const int fo = (K == 216) ? (kc >= 3 ? (kc - 3) * F4C : kc * F4C) : kc * F4C;
    const float4* __restrict__ src4 = (const float4*)srcA;
#pragma unroll
    for (int it = 0; it < (128 * F4C + 255) / 256; it++) {
      int idx = tid + it * 256;
      if (idx < 128 * F4C) {
        int r = idx / F4C, f = idx - r * F4C;
        int gn = n0 + r;
        float4 v = {0.f, 0.f, 0.f, 0.f};
        if (gn < N) v = src4[(size_t)gn * RowF4 + fo + f];
        *(float4*)&As[r * AST + f * 4] = v;
      }
    }
    // ---- stage W chunk: KC rows x 28 float4 (col 27 zero-pad) ----
    const float4* __restrict__ Wg4 = (const float4*)Wg;
    const int k0 = kc * KC;
#pragma unroll
    for (int it = 0; it < (KC * 28 + 255) / 256; it++) {
      int idx = tid + it * 256;
      if (idx < KC * 28) {
        int k = idx / 28, c = idx - k * 28;
        float4 v = {0.f, 0.f, 0.f, 0.f};
        if (c < 27) v = Wg4[(size_t)(k0 + k) * 27 + c];
        *(float4*)&Ws[k * 112 + c * 4] = v;
      }
    }
    __syncthreads();

#pragma unroll 4
    for (int k = 0; k < KC; k++) {
      float4 w = *(const float4*)&Ws[k * 112 + coc * 4];
#pragma unroll
      for (int m = 0; m < 16; m++) {
        float a = As[(nr + m * 8) * AST + k];
        acc[m][0] = fmaf(a, w.x, acc[m][0]);
        acc[m][1] = fmaf(a, w.y, acc[m][1]);
        acc[m][2] = fmaf(a, w.z, acc[m][2]);
        acc[m][3] = fmaf(a, w.w, acc[m][3]);
      }
    }
    __syncthreads();
  }

  // ---- epilogue ----
  float4 bias4 = {0.f, 0.f, 0.f, 0.f};
  if (co < 27) bias4 = *(const float4*)&bias[co * 4];
  float4* out4 = (float4*)out;

  if (MODE == 2) {
#pragma unroll 1
    for (int m = 0; m < 16; m++) {
      int gn = n0 + nr + m * 8;
      float b0 = 0.f, b1 = 0.f, b2 = 0.f, b3 = 0.f;
      if (co < 27) {
        b0 = acc[m][0] + bias4.x;
        b1 = acc[m][1] + bias4.y;
        b2 = acc[m][2] + bias4.z;
        b3 = acc[m][3] + bias4.w;
      }
      float ssq = b0 * b0 + b1 * b1 + b2 * b2 + b3 * b3;
#pragma unroll
      for (int s = 1; s < 32; s <<= 1) ssq += __shfl_xor(ssq, s, 32);
      float scale = 1.f / fmaxf(sqrtf(ssq), 1e-12f);
      if (gn < N && co < 27) {
        float4 hv = out4[(size_t)gn * 27 + co];
        float4 r;
        r.x = hv.x + fmaxf(b0 * scale, 0.f);
        r.y = hv.y + fmaxf(b1 * scale, 0.f);
        r.z = hv.z + fmaxf(b2 * scale, 0.f);
        r.w = hv.w + fmaxf(b3 * scale, 0.f);
        out4[(size_t)gn * 27 + co] = r;
      }
    }
  } else {
#pragma unroll 1
    for (int m = 0; m < 16; m++) {
      int gn = n0 + nr + m * 8;
      if (gn < N && co < 27) {
        float4 r;
        r.x = acc[m][0] + bias4.x;
        r.y = acc[m][1] + bias4.y;
        r.z = acc[m][2] + bias4.z;
        r.w = acc[m][3] + bias4.w;
        if (MODE == 1) {
          r.x = fmaxf(r.x, 0.f); r.y = fmaxf(r.y, 0.f);
          r.z = fmaxf(r.z, 0.f); r.w = fmaxf(r.w, 0.f);
        }
        out4[(size_t)gn * 27 + co] = r;
      }
    }
  }
}

// ---------------- edge aggregation: c[v] = mean_{e: dst==v} z[src[e]] ----------------
// float4: 108 floats = 27 float4. 32-lane group per node (27 active), 8 nodes/block.
__global__ __launch_bounds__(256) void k_agg(const float* __restrict__ z, const int* __restrict__ csr,
                                             const int* __restrict__ rowStart, const int* __restrict__ deg,
                                             float* __restrict__ c, int N) {
  const int lane = threadIdx.x & 31;
  const int grp = threadIdx.x >> 5;
  const int v = blockIdx.x * 8 + grp;
  if (v >= N || lane >= 27) return;
  const float4* __restrict__ z4 = (const float4*)z;
  int rs = rowStart[v];
  int d = deg[v];
  const int* nb = csr + rs;
  float4 acc = {0.f, 0.f, 0.f, 0.f};
  int j = 0;
  for (; j + 4 <= d; j += 4) {
    int s0 = nb[j], s1 = nb[j + 1], s2 = nb[j + 2], s3 = nb[j + 3];
    float4 v0 = z4[(size_t)s0 * 27 + lane];
    float4 v1 = z4[(size_t)s1 * 27 + lane];
    float4 v2 = z4[(size_t)s2 * 27 + lane];
    float4 v3 = z4[(size_t)s3 * 27 + lane];
    acc.x += v0.x + v1.x + v2.x + v3.x;
    acc.y += v0.y + v1.y + v2.y + v3.y;
    acc.z += v0.z + v1.z + v2.z + v3.z;
    acc.w += v0.w + v1.w + v2.w + v3.w;
  }
  for (; j < d; j++) {
    float4 v0 = z4[(size_t)nb[j] * 27 + lane];
    acc.x += v0.x; acc.y += v0.y; acc.z += v0.z; acc.w += v0.w;
  }
  float dn = (d > 0) ? (float)d : 1.f;
  float inv = 1.f / dn;
  float4* c4 = (float4*)c;
  float4 r;
  r.x = acc.x * inv; r.y = acc.y * inv; r.z = acc.z * inv; r.w = acc.w * inv;
  c4[(size_t)v * 27 + lane] = r;
}

// ---------------- readout ----------------
__global__ __launch_bounds__(128) void k_cnt_bs(const int* __restrict__ gid, int* __restrict__ cnt, int N) {
  int g = threadIdx.x;
  if (g >= G_GRAPHS) return;
  int lo = 0, hi = N;
  while (lo < hi) { int m = (lo + hi) >> 1; if (gid[m] < g) lo = m + 1; else hi = m; }
  int lb = lo;
  lo = 0; hi = N;
  while (lo < hi) { int m = (lo + hi) >> 1; if (gid[m] <= g) lo = m + 1; else hi = m; }
  cnt[g] = lo - lb;
}

__global__ __launch_bounds__(256) void k_readout(const float* __restrict__ h, const int* __restrict__ gid,
                                                 float* __restrict__ hg, int N) {
  const int CH = 64;
  const int lane = threadIdx.x & 31;
  const int grp = threadIdx.x >> 5;
  int start = (blockIdx.x * 8 + grp) * CH;
  if (start >= N || lane >= 27) return;
  int end = min(start + CH, N);
  const float4* __restrict__ h4 = (const float4*)h;
  float4 acc = {0.f, 0.f, 0.f, 0.f};
  int cur = gid[start];  // sorted graph_ids -> run-length pre-aggregation
  for (int i = start; i < end; i++) {
    int g = gid[i];
    if (g != cur) {
      float* base = &hg[(size_t)cur * HDIM + lane * 4];
      atomicAdd(base + 0, acc.x); atomicAdd(base + 1, acc.y);
      atomicAdd(base + 2, acc.z); atomicAdd(base + 3, acc.w);
      acc.x = acc.y = acc.z = acc.w = 0.f;
      cur = g;
    }
    float4 v = h4[(size_t)i * 27 + lane];
    acc.x += v.x; acc.y += v.y; acc.z += v.z; acc.w += v.w;
  }
  float* base = &hg[(size_t)cur * HDIM + lane * 4];
  atomicAdd(base + 0, acc.x); atomicAdd(base + 1, acc.y);
  atomicAdd(base + 2, acc.z); atomicAdd(base + 3, acc.w);
}

__global__ __launch_bounds__(256) void k_div(const float* __restrict__ hg, const int* __restrict__ cnt,
                                             float* __restrict__ out, int total) {
  int i = blockIdx.x * 256 + threadIdx.x;
  if (i < total) {
    int g = i / HDIM;
    int c = cnt[g];
    out[i] = hg[i] / (float)(c > 0 ? c : 1);
  }
}

// ---------------- launch ----------------
extern "C" void kernel_launch(void* const* d_in, const int* in_sizes, int n_in,
                              void* d_out, int out_size, void* d_ws, size_t ws_size,
                              hipStream_t stream) {
  (void)n_in; (void)ws_size; (void)out_size;
  const float* nodes_feat = (const float*)d_in[0];
  const float* W_emb = (const float*)d_in[4];
  const float* b_emb = (const float*)d_in[5];
  const float* pool_W = (const float*)d_in[6];
  const float* pool_b = (const float*)d_in[7];
  const float* app_W = (const float*)d_in[8];
  const float* app_b = (const float*)d_in[9];
  const int* src = (const int*)d_in[10];
  const int* dst = (const int*)d_in[11];
  const int* gid = (const int*)d_in[12];
  const int N = in_sizes[2];
  const int E = in_sizes[10];
  float* out = (float*)d_out;

  char* ws = (char*)d_ws;
  size_t off = 0;
  auto alloc = [&](size_t bytes) -> size_t {
    size_t o = off;
    off += (bytes + 1023) & ~size_t(1023);
    return o;
  };
  size_t o_deg = alloc((size_t)N * 4);
  size_t o_cnt = alloc((size_t)G_GRAPHS * 4);
  size_t o_hg  = alloc((size_t)G_GRAPHS * HDIM * 4);
  size_t zero_bytes = off;  // [deg, cnt, hg] zeroed in one memset
  size_t o_rs   = alloc((size_t)N * 4);
  size_t o_cur  = alloc((size_t)N * 4);
  size_t o_csr  = alloc((size_t)E * 4);
  size_t o_bsum = alloc(2048);
  size_t o_boff = alloc(2048);
  size_t o_h = alloc((size_t)N * HDIM * 4);
  size_t o_z = alloc((size_t)N * HDIM * 4);
  size_t o_c = alloc((size_t)N * HDIM * 4);

  int* deg      = (int*)(ws + o_deg);
  int* cnt      = (int*)(ws + o_cnt);
  float* hg     = (float*)(ws + o_hg);
  int* rowStart = (int*)(ws + o_rs);
  int* cursor   = (int*)(ws + o_cur);
  int* csr      = (int*)(ws + o_csr);
  int* bsum     = (int*)(ws + o_bsum);
  int* boff     = (int*)(ws + o_boff);
  float* h = (float*)(ws + o_h);
  float* z = (float*)(ws + o_z);
  float* c = (float*)(ws + o_c);

  hipMemsetAsync(d_ws, 0, zero_bytes, stream);

  const int nbE = (E + 255) / 256;
  const int nbN = (N + 255) / 256;  // 391 <= 512 (single-block top scan)
  k_deg<<<nbE, 256, 0, stream>>>(dst, deg, E);
  k_blocksum<<<nbN, 256, 0, stream>>>(deg, bsum, N);
  k_scan_bsum<<<1, 512, 0, stream>>>(bsum, boff, nbN);
  k_scan_final<<<nbN, 256, 0, stream>>>(deg, boff, rowStart, cursor, N);
  k_fill<<<nbE, 256, 0, stream>>>(src, dst, cursor, csr, E);

  const int nbMM = (N + 127) / 128;
  k_mm<64, 32, 0><<<nbMM, 256, 0, stream>>>(nodes_feat, nullptr, W_emb, b_emb, h, N);

  for (int i = 0; i < 2; i++) {
    k_mm<108, 36, 1><<<nbMM, 256, 0, stream>>>(h, nullptr, pool_W + i * HDIM * HDIM,
                                               pool_b + i * HDIM, z, N);
    k_agg<<<(N + 7) / 8, 256, 0, stream>>>(z, csr, rowStart, deg, c, N);
    k_mm<216, 36, 2><<<nbMM, 256, 0, stream>>>(h, c, app_W + i * 2 * HDIM * HDIM,
                                               app_b + i * HDIM, h, N);
  }

  k_cnt_bs<<<1, 128, 0, stream>>>(gid, cnt, N);
  k_readout<<<(N + 8 * 64 - 1) / (8 * 64), 256, 0, stream>>>(h, gid, hg, N);
  k_div<<<(G_GRAPHS * HDIM + 255) / 256, 256, 0, stream>>>(hg, cnt, out, G_GRAPHS * HDIM);
}

// Round 4
// 893.467 us; speedup vs baseline: 1.7949x; 1.7949x over previous
//
#include <hip/hip_runtime.h>

#define HDIM 108
constexpr int G_GRAPHS = 128;

// ---------------- CSR build ----------------

__global__ __launch_bounds__(256) void k_deg(const int* __restrict__ dst, int* __restrict__ deg, int E) {
  int e = blockIdx.x * 256 + threadIdx.x;
  if (e < E) atomicAdd(&deg[dst[e]], 1);
}

__global__ __launch_bounds__(256) void k_blocksum(const int* __restrict__ deg, int* __restrict__ bsum, int N) {
  __shared__ int s[256];
  int t = threadIdx.x;
  int i = blockIdx.x * 256 + t;
  s[t] = (i < N) ? deg[i] : 0;
  __syncthreads();
  for (int off = 128; off > 0; off >>= 1) {
    if (t < off) s[t] += s[t + off];
    __syncthreads();
  }
  if (t == 0) bsum[blockIdx.x] = s[0];
}

__global__ __launch_bounds__(512) void k_scan_bsum(const int* __restrict__ bsum, int* __restrict__ boff, int nb) {
  __shared__ int s[512];
  int t = threadIdx.x;
  int own = (t < nb) ? bsum[t] : 0;
  s[t] = own;
  __syncthreads();
  for (int off = 1; off < 512; off <<= 1) {
    int x = (t >= off) ? s[t - off] : 0;
    __syncthreads();
    s[t] += x;
    __syncthreads();
  }
  if (t < nb) boff[t] = s[t] - own;  // exclusive
}

__global__ __launch_bounds__(256) void k_scan_final(const int* __restrict__ deg, const int* __restrict__ boff,
                                                    int* __restrict__ rowStart, int* __restrict__ cursor, int N) {
  __shared__ int s[256];
  int t = threadIdx.x;
  int i = blockIdx.x * 256 + t;
  int own = (i < N) ? deg[i] : 0;
  s[t] = own;
  __syncthreads();
  for (int off = 1; off < 256; off <<= 1) {
    int x = (t >= off) ? s[t - off] : 0;
    __syncthreads();
    s[t] += x;
    __syncthreads();
  }
  if (i < N) {
    int rs = boff[blockIdx.x] + s[t] - own;
    rowStart[i] = rs;
    cursor[i] = rs;
  }
}

__global__ __launch_bounds__(256) void k_fill(const int* __restrict__ src, const int* __restrict__ dst,
                                              int* __restrict__ cursor, int* __restrict__ csr, int E) {
  int e = blockIdx.x * 256 + threadIdx.x;
  if (e < E) {
    int pos = atomicAdd(&cursor[dst[e]], 1);
    csr[pos] = src[e];  // store source node id directly
  }
}

// ---------------- GEMM: out[N,108] = A[N,K] @ W[K,108] (+bias, act) ----------------
// Block 256 threads, tile 64 nodes x 108 cols. Thread: co=tid&31 (float4 col group,
// 27 active), nr=tid>>5; 8 nodes (nr+m*8) x 4 consecutive cols -> acc[8][4]=32 VGPR
// (fits any reg cap; launch_bounds(256,2) opens budget to avoid scratch spill).
// Inner loop: A read as float4 along K (broadcast), W as float4 along cols.
// MODE 0: +bias. MODE 1: +bias,ReLU. MODE 2: +bias -> row L2 norm -> ReLU -> residual (in-place h).

template <int K, int KC, int MODE>
__global__ __launch_bounds__(256, 2) void k_mm(const float* A, const float* __restrict__ A2,
                                               const float* __restrict__ Wg, const float* __restrict__ bias,
                                               float* out, int N) {
  constexpr int NCH = K / KC;            // chunks
  constexpr int F4C = KC / 4;            // float4 per row chunk
  constexpr int AST = KC + 4;            // As row stride in floats (16B-aligned pad)
  constexpr int RowF4 = (K == 64) ? 16 : 27;  // source row length in float4
  __shared__ float As[64 * AST];
  __shared__ float Ws[KC * 112 + 16];    // +slack for clamped-lane b128 reads

  const int tid = threadIdx.x;
  const int co = tid & 31;
  const int coc = (co < 27) ? co : 26;   // clamp idle lanes
  const int nr = tid >> 5;               // 0..7
  const int n0 = blockIdx.x * 64;

  float acc[8][4];
#pragma unroll
  for (int m = 0; m < 8; m++)
#pragma unroll
    for (int j = 0; j < 4; j++) acc[m][j] = 0.f;

#pragma unroll 1
  for (int kc = 0; kc < NCH; kc++) {
    // ---- stage A chunk: 64 rows x F4C float4 ----
    const float* srcA = (K == 216 && kc >= 3) ? A2 : A;
    const int fo = (K == 216) ? (kc >= 3 ? (kc - 3) * F4C : kc * F4C) : kc * F4C;
    const float4* __restrict__ src4 = (const float4*)srcA;
#pragma unroll
    for (int it = 0; it < (64 * F4C + 255) / 256; it++) {
      int idx = tid + it * 256;
      if (idx < 64 * F4C) {
        int r = idx / F4C, f = idx - r * F4C;
        int gn = n0 + r;
        float4 v = {0.f, 0.f, 0.f, 0.f};
        if (gn < N) v = src4[(size_t)gn * RowF4 + fo + f];
        *(float4*)&As[r * AST + f * 4] = v;
      }
    }
    // ---- stage W chunk: KC rows x 28 float4 (col group 27 zero-pad) ----
    const float4* __restrict__ Wg4 = (const float4*)Wg;
    const int k0 = kc * KC;
#pragma unroll
    for (int it = 0; it < (KC * 28 + 255) / 256; it++) {
      int idx = tid + it * 256;
      if (idx < KC * 28) {
        int k = idx / 28, c = idx - k * 28;
        float4 v = {0.f, 0.f, 0.f, 0.f};
        if (c < 27) v = Wg4[(size_t)(k0 + k) * 27 + c];
        *(float4*)&Ws[k * 112 + c * 4] = v;
      }
    }
    __syncthreads();

#pragma unroll
    for (int k4 = 0; k4 < F4C; k4++) {
      float4 w0 = *(const float4*)&Ws[(k4 * 4 + 0) * 112 + coc * 4];
      float4 w1 = *(const float4*)&Ws[(k4 * 4 + 1) * 112 + coc * 4];
      float4 w2 = *(const float4*)&Ws[(k4 * 4 + 2) * 112 + coc * 4];
      float4 w3 = *(const float4*)&Ws[(k4 * 4 + 3) * 112 + coc * 4];
#pragma unroll
      for (int m = 0; m < 8; m++) {
        float4 a = *(const float4*)&As[(nr + m * 8) * AST + k4 * 4];
        acc[m][0] = fmaf(a.x, w0.x, acc[m][0]);
        acc[m][1] = fmaf(a.x, w0.y, acc[m][1]);
        acc[m][2] = fmaf(a.x, w0.z, acc[m][2]);
        acc[m][3] = fmaf(a.x, w0.w, acc[m][3]);
        acc[m][0] = fmaf(a.y, w1.x, acc[m][0]);
        acc[m][1] = fmaf(a.y, w1.y, acc[m][1]);
        acc[m][2] = fmaf(a.y, w1.z, acc[m][2]);
        acc[m][3] = fmaf(a.y, w1.w, acc[m][3]);
        acc[m][0] = fmaf(a.z, w2.x, acc[m][0]);
        acc[m][1] = fmaf(a.z, w2.y, acc[m][1]);
        acc[m][2] = fmaf(a.z, w2.z, acc[m][2]);
        acc[m][3] = fmaf(a.z, w2.w, acc[m][3]);
        acc[m][0] = fmaf(a.w, w3.x, acc[m][0]);
        acc[m][1] = fmaf(a.w, w3.y, acc[m][1]);
        acc[m][2] = fmaf(a.w, w3.z, acc[m][2]);
        acc[m][3] = fmaf(a.w, w3.w, acc[m][3]);
      }
    }
    __syncthreads();
  }

  // ---- epilogue ----
  float4 bias4 = {0.f, 0.f, 0.f, 0.f};
  if (co < 27) bias4 = *(const float4*)&bias[co * 4];
  float4* out4 = (float4*)out;

  if (MODE == 2) {
#pragma unroll 1
    for (int m = 0; m < 8; m++) {
      int gn = n0 + nr + m * 8;
      float b0 = 0.f, b1 = 0.f, b2 = 0.f, b3 = 0.f;
      if (co < 27) {
        b0 = acc[m][0] + bias4.x;
        b1 = acc[m][1] + bias4.y;
        b2 = acc[m][2] + bias4.z;
        b3 = acc[m][3] + bias4.w;
      }
      float ssq = b0 * b0 + b1 * b1 + b2 * b2 + b3 * b3;
#pragma unroll
      for (int s = 1; s < 32; s <<= 1) ssq += __shfl_xor(ssq, s, 32);
      float scale = 1.f / fmaxf(sqrtf(ssq), 1e-12f);
      if (gn < N && co < 27) {
        float4 hv = out4[(size_t)gn * 27 + co];
        float4 r;
        r.x = hv.x + fmaxf(b0 * scale, 0.f);
        r.y = hv.y + fmaxf(b1 * scale, 0.f);
        r.z = hv.z + fmaxf(b2 * scale, 0.f);
        r.w = hv.w + fmaxf(b3 * scale, 0.f);
        out4[(size_t)gn * 27 + co] = r;
      }
    }
  } else {
#pragma unroll 1
    for (int m = 0; m < 8; m++) {
      int gn = n0 + nr + m * 8;
      if (gn < N && co < 27) {
        float4 r;
        r.x = acc[m][0] + bias4.x;
        r.y = acc[m][1] + bias4.y;
        r.z = acc[m][2] + bias4.z;
        r.w = acc[m][3] + bias4.w;
        if (MODE == 1) {
          r.x = fmaxf(r.x, 0.f); r.y = fmaxf(r.y, 0.f);
          r.z = fmaxf(r.z, 0.f); r.w = fmaxf(r.w, 0.f);
        }
        out4[(size_t)gn * 27 + co] = r;
      }
    }
  }
}

// ---------------- edge aggregation: c[v] = mean_{e: dst==v} z[src[e]] ----------------
__global__ __launch_bounds__(256) void k_agg(const float* __restrict__ z, const int* __restrict__ csr,
                                             const int* __restrict__ rowStart, const int* __restrict__ deg,
                                             float* __restrict__ c, int N) {
  const int lane = threadIdx.x & 31;
  const int grp = threadIdx.x >> 5;
  const int v = blockIdx.x * 8 + grp;
  if (v >= N || lane >= 27) return;
  const float4* __restrict__ z4 = (const float4*)z;
  int rs = rowStart[v];
  int d = deg[v];
  const int* nb = csr + rs;
  float4 acc = {0.f, 0.f, 0.f, 0.f};
  int j = 0;
  for (; j + 4 <= d; j += 4) {
    int s0 = nb[j], s1 = nb[j + 1], s2 = nb[j + 2], s3 = nb[j + 3];
    float4 v0 = z4[(size_t)s0 * 27 + lane];
    float4 v1 = z4[(size_t)s1 * 27 + lane];
    float4 v2 = z4[(size_t)s2 * 27 + lane];
    float4 v3 = z4[(size_t)s3 * 27 + lane];
    acc.x += v0.x + v1.x + v2.x + v3.x;
    acc.y += v0.y + v1.y + v2.y + v3.y;
    acc.z += v0.z + v1.z + v2.z + v3.z;
    acc.w += v0.w + v1.w + v2.w + v3.w;
  }
  for (; j < d; j++) {
    float4 v0 = z4[(size_t)nb[j] * 27 + lane];
    acc.x += v0.x; acc.y += v0.y; acc.z += v0.z; acc.w += v0.w;
  }
  float dn = (d > 0) ? (float)d : 1.f;
  float inv = 1.f / dn;
  float4* c4 = (float4*)c;
  float4 r;
  r.x = acc.x * inv; r.y = acc.y * inv; r.z = acc.z * inv; r.w = acc.w * inv;
  c4[(size_t)v * 27 + lane] = r;
}

// ---------------- readout ----------------
__global__ __launch_bounds__(128) void k_cnt_bs(const int* __restrict__ gid, int* __restrict__ cnt, int N) {
  int g = threadIdx.x;
  if (g >= G_GRAPHS) return;
  int lo = 0, hi = N;
  while (lo < hi) { int m = (lo + hi) >> 1; if (gid[m] < g) lo = m + 1; else hi = m; }
  int lb = lo;
  lo = 0; hi = N;
  while (lo < hi) { int m = (lo + hi) >> 1; if (gid[m] <= g) lo = m + 1; else hi = m; }
  cnt[g] = lo - lb;
}

__global__ __launch_bounds__(256) void k_readout(const float* __restrict__ h, const int* __restrict__ gid,
                                                 float* __restrict__ hg, int N) {
  const int CH = 64;
  const int lane = threadIdx.x & 31;
  const int grp = threadIdx.x >> 5;
  int start = (blockIdx.x * 8 + grp) * CH;
  if (start >= N || lane >= 27) return;
  int end = min(start + CH, N);
  const float4* __restrict__ h4 = (const float4*)h;
  float4 acc = {0.f, 0.f, 0.f, 0.f};
  int cur = gid[start];  // sorted graph_ids -> run-length pre-aggregation
  for (int i = start; i < end; i++) {
    int g = gid[i];
    if (g != cur) {
      float* base = &hg[(size_t)cur * HDIM + lane * 4];
      atomicAdd(base + 0, acc.x); atomicAdd(base + 1, acc.y);
      atomicAdd(base + 2, acc.z); atomicAdd(base + 3, acc.w);
      acc.x = acc.y = acc.z = acc.w = 0.f;
      cur = g;
    }
    float4 v = h4[(size_t)i * 27 + lane];
    acc.x += v.x; acc.y += v.y; acc.z += v.z; acc.w += v.w;
  }
  float* base = &hg[(size_t)cur * HDIM + lane * 4];
  atomicAdd(base + 0, acc.x); atomicAdd(base + 1, acc.y);
  atomicAdd(base + 2, acc.z); atomicAdd(base + 3, acc.w);
}

__global__ __launch_bounds__(256) void k_div(const float* __restrict__ hg, const int* __restrict__ cnt,
                                             float* __restrict__ out, int total) {
  int i = blockIdx.x * 256 + threadIdx.x;
  if (i < total) {
    int g = i / HDIM;
    int c = cnt[g];
    out[i] = hg[i] / (float)(c > 0 ? c : 1);
  }
}

// ---------------- launch ----------------
extern "C" void kernel_launch(void* const* d_in, const int* in_sizes, int n_in,
                              void* d_out, int out_size, void* d_ws, size_t ws_size,
                              hipStream_t stream) {
  (void)n_in; (void)ws_size; (void)out_size;
  const float* nodes_feat = (const float*)d_in[0];
  const float* W_emb = (const float*)d_in[4];
  const float* b_emb = (const float*)d_in[5];
  const float* pool_W = (const float*)d_in[6];
  const float* pool_b = (const float*)d_in[7];
  const float* app_W = (const float*)d_in[8];
  const float* app_b = (const float*)d_in[9];
  const int* src = (const int*)d_in[10];
  const int* dst = (const int*)d_in[11];
  const int* gid = (const int*)d_in[12];
  const int N = in_sizes[2];
  const int E = in_sizes[10];
  float* out = (float*)d_out;

  char* ws = (char*)d_ws;
  size_t off = 0;
  auto alloc = [&](size_t bytes) -> size_t {
    size_t o = off;
    off += (bytes + 1023) & ~size_t(1023);
    return o;
  };
  size_t o_deg = alloc((size_t)N * 4);
  size_t o_cnt = alloc((size_t)G_GRAPHS * 4);
  size_t o_hg  = alloc((size_t)G_GRAPHS * HDIM * 4);
  size_t zero_bytes = off;  // [deg, cnt, hg] zeroed in one memset
  size_t o_rs   = alloc((size_t)N * 4);
  size_t o_cur  = alloc((size_t)N * 4);
  size_t o_csr  = alloc((size_t)E * 4);
  size_t o_bsum = alloc(2048);
  size_t o_boff = alloc(2048);
  size_t o_h = alloc((size_t)N * HDIM * 4);
  size_t o_z = alloc((size_t)N * HDIM * 4);
  size_t o_c = alloc((size_t)N * HDIM * 4);

  int* deg      = (int*)(ws + o_deg);
  int* cnt      = (int*)(ws + o_cnt);
  float* hg     = (float*)(ws + o_hg);
  int* rowStart = (int*)(ws + o_rs);
  int* cursor   = (int*)(ws + o_cur);
  int* csr      = (int*)(ws + o_csr);
  int* bsum     = (int*)(ws + o_bsum);
  int* boff     = (int*)(ws + o_boff);
  float* h = (float*)(ws + o_h);
  float* z = (float*)(ws + o_z);
  float* c = (float*)(ws + o_c);

  hipMemsetAsync(d_ws, 0, zero_bytes, stream);

  const int nbE = (E + 255) / 256;
  const int nbN = (N + 255) / 256;  // 391 <= 512 (single-block top scan)
  k_deg<<<nbE, 256, 0, stream>>>(dst, deg, E);
  k_blocksum<<<nbN, 256, 0, stream>>>(deg, bsum, N);
  k_scan_bsum<<<1, 512, 0, stream>>>(bsum, boff, nbN);
  k_scan_final<<<nbN, 256, 0, stream>>>(deg, boff, rowStart, cursor, N);
  k_fill<<<nbE, 256, 0, stream>>>(src, dst, cursor, csr, E);

  const int nbMM = (N + 63) / 64;
  k_mm<64, 32, 0><<<nbMM, 256, 0, stream>>>(nodes_feat, nullptr, W_emb, b_emb, h, N);

  for (int i = 0; i < 2; i++) {
    k_mm<108, 36, 1><<<nbMM, 256, 0, stream>>>(h, nullptr, pool_W + i * HDIM * HDIM,
                                               pool_b + i * HDIM, z, N);
    k_agg<<<(N + 7) / 8, 256, 0, stream>>>(z, csr, rowStart, deg, c, N);
    k_mm<216, 36, 2><<<nbMM, 256, 0, stream>>>(h, c, app_W + i * 2 * HDIM * HDIM,
                                               app_b + i * HDIM, h, N);
  }

  k_cnt_bs<<<1, 128, 0, stream>>>(gid, cnt, N);
  k_readout<<<(N + 8 * 64 - 1) / (8 * 64), 256, 0, stream>>>(h, gid, hg, N);
  k_div<<<(G_GRAPHS * HDIM + 255) / 256, 256, 0, stream>>>(hg, cnt, out, G_GRAPHS * HDIM);
}

// Round 5
// 681.215 us; speedup vs baseline: 2.3541x; 1.3116x over previous
//
#include <hip/hip_runtime.h>
#include <hip/hip_fp16.h>

#define HDIM 108
constexpr int G_GRAPHS = 128;
constexpr int MAXNB = 1024;   // max buckets (N up to 131072)
constexpr int CAP = 2560;     // slots per bucket (mean 2048, sigma ~45 -> +11 sigma)

// ---------------- bucket partition: edges -> (src,dst) pairs grouped by dst>>7 ----------------
// One kernel replaces deg/scan/fill. gcur[b*16] is a 64B-strided global rank counter
// (stride kills cross-XCD line ping-pong on the atomics).
__global__ __launch_bounds__(256) void k_scatter(const int* __restrict__ src, const int* __restrict__ dst,
                                                 int* __restrict__ gcur, int2* __restrict__ ebuf,
                                                 int E, int nb) {
  __shared__ int hist[MAXNB];
  const int tid = threadIdx.x;
  const int e0 = blockIdx.x * 4096;
  for (int b = tid; b < nb; b += 256) hist[b] = 0;
  __syncthreads();
#pragma unroll
  for (int it = 0; it < 16; it++) {
    int e = e0 + it * 256 + tid;
    if (e < E) atomicAdd(&hist[dst[e] >> 7], 1);
  }
  __syncthreads();
  // reserve [base, base+h) in bucket b; hist[b] becomes the running global rank
  for (int b = tid; b < nb; b += 256) {
    int h = hist[b];
    hist[b] = h ? atomicAdd(&gcur[b * 16], h) : 0;
  }
  __syncthreads();
#pragma unroll
  for (int it = 0; it < 16; it++) {
    int e = e0 + it * 256 + tid;
    if (e < E) {
      int d = dst[e];
      int b = d >> 7;
      int rank = atomicAdd(&hist[b], 1);
      if (rank < CAP) ebuf[(size_t)b * CAP + rank] = make_int2(src[e], d);
    }
  }
}

// ---------------- bucket aggregation: c[v] = mean_{e: dst==v} z[src[e]] ----------------
// One block per bucket (128 nodes). LDS counting-sort edges by local dst -> micro-CSR,
// then 32-lane groups gather fp16 z rows per node (8B/lane) and write fp32 c.
__global__ __launch_bounds__(256) void k_bagg(const __half* __restrict__ z, const int2* __restrict__ ebuf,
                                              const int* __restrict__ gcur, float* __restrict__ c,
                                              int N, int nb) {
  __shared__ int cnts[128];
  __shared__ int scanb[128];
  __shared__ int off[129];
  __shared__ int ecur[128];
  __shared__ int esrc[CAP];
  const int tid = threadIdx.x;
  const int b = blockIdx.x;
  const int v0 = b << 7;
  int cntb = gcur[b * 16];
  if (cntb > CAP) cntb = CAP;
  const int2* eb = ebuf + (size_t)b * CAP;

  if (tid < 128) cnts[tid] = 0;
  __syncthreads();
  for (int i = tid; i < cntb; i += 256) atomicAdd(&cnts[eb[i].y & 127], 1);
  __syncthreads();
  if (tid < 128) scanb[tid] = cnts[tid];
  __syncthreads();
#pragma unroll
  for (int st = 1; st < 128; st <<= 1) {
    int v = 0;
    if (tid < 128 && tid >= st) v = scanb[tid - st];
    __syncthreads();
    if (tid < 128) scanb[tid] += v;
    __syncthreads();
  }
  if (tid == 0) off[0] = 0;
  if (tid < 128) {
    off[tid + 1] = scanb[tid];
    ecur[tid] = scanb[tid] - cnts[tid];
  }
  __syncthreads();
  for (int i = tid; i < cntb; i += 256) {
    int2 e = eb[i];
    int p = atomicAdd(&ecur[e.y & 127], 1);
    esrc[p] = e.x;
  }
  __syncthreads();

  const int lane = tid & 31;
  const int grp = tid >> 5;                 // 8 groups of 32 (27 active lanes)
  const int lc = (lane < 27) ? lane : 26;
  float4* __restrict__ c4 = (float4*)c;
#pragma unroll 1
  for (int r = grp; r < 128; r += 8) {
    int v = v0 + r;
    if (v >= N) continue;
    int s = off[r], e2 = off[r + 1];
    float a0 = 0.f, a1 = 0.f, a2 = 0.f, a3 = 0.f;
    int j = s;
    for (; j + 2 <= e2; j += 2) {
      int s0 = esrc[j], s1 = esrc[j + 1];
      uint2 q0 = *(const uint2*)(z + (size_t)s0 * HDIM + lc * 4);
      uint2 q1 = *(const uint2*)(z + (size_t)s1 * HDIM + lc * 4);
      float2 f0 = __half22float2(*(__half2*)&q0.x);
      float2 g0 = __half22float2(*(__half2*)&q0.y);
      float2 f1 = __half22float2(*(__half2*)&q1.x);
      float2 g1 = __half22float2(*(__half2*)&q1.y);
      a0 += f0.x + f1.x; a1 += f0.y + f1.y;
      a2 += g0.x + g1.x; a3 += g0.y + g1.y;
    }
    if (j < e2) {
      uint2 q0 = *(const uint2*)(z + (size_t)esrc[j] * HDIM + lc * 4);
      float2 f0 = __half22float2(*(__half2*)&q0.x);
      float2 g0 = __half22float2(*(__half2*)&q0.y);
      a0 += f0.x; a1 += f0.y; a2 += g0.x; a3 += g0.y;
    }
    int d = e2 - s;
    float inv = 1.f / (float)(d > 0 ? d : 1);
    if (lane < 27) {
      float4 r4;
      r4.x = a0 * inv; r4.y = a1 * inv; r4.z = a2 * inv; r4.w = a3 * inv;
      c4[(size_t)v * 27 + lane] = r4;
    }
  }
}

// ---------------- GEMM: out[N,108] = A[N,K] @ W[K,108] (+bias, act) ----------------
// Block 256 threads, tile 64 nodes x 108 cols; acc[8][4]=32 VGPR (no spill; lb(256,2)).
// MODE 0: +bias (fp32 out). MODE 2: +bias -> row L2 norm -> ReLU -> residual (in-place fp32 h).
// MODE 3: +bias, ReLU, store fp16 (z).
template <int K, int KC, int MODE>
__global__ __launch_bounds__(256, 2) void k_mm(const float* A, const float* __restrict__ A2,
                                               const float* __restrict__ Wg, const float* __restrict__ bias,
                                               float* out, int N) {
  constexpr int NCH = K / KC;
  constexpr int F4C = KC / 4;
  constexpr int AST = KC + 4;
  constexpr int RowF4 = (K == 64) ? 16 : 27;
  __shared__ float As[64 * AST];
  __shared__ float Ws[KC * 112 + 16];

  const int tid = threadIdx.x;
  const int co = tid & 31;
  const int coc = (co < 27) ? co : 26;
  const int nr = tid >> 5;
  const int n0 = blockIdx.x * 64;

  float acc[8][4];
#pragma unroll
  for (int m = 0; m < 8; m++)
#pragma unroll
    for (int j = 0; j < 4; j++) acc[m][j] = 0.f;

#pragma unroll 1
  for (int kc = 0; kc < NCH; kc++) {
    const float* srcA = (K == 216 && kc >= 3) ? A2 : A;
    const int fo = (K == 216) ? (kc >= 3 ? (kc - 3) * F4C : kc * F4C) : kc * F4C;
    const float4* __restrict__ src4 = (const float4*)srcA;
#pragma unroll
    for (int it = 0; it < (64 * F4C + 255) / 256; it++) {
      int idx = tid + it * 256;
      if (idx < 64 * F4C) {
        int r = idx / F4C, f = idx - r * F4C;
        int gn = n0 + r;
        float4 v = {0.f, 0.f, 0.f, 0.f};
        if (gn < N) v = src4[(size_t)gn * RowF4 + fo + f];
        *(float4*)&As[r * AST + f * 4] = v;
      }
    }
    const float4* __restrict__ Wg4 = (const float4*)Wg;
    const int k0 = kc * KC;
#pragma unroll
    for (int it = 0; it < (KC * 28 + 255) / 256; it++) {
      int idx = tid + it * 256;
      if (idx < KC * 28) {
        int k = idx / 28, cc = idx - k * 28;
        float4 v = {0.f, 0.f, 0.f, 0.f};
        if (cc < 27) v = Wg4[(size_t)(k0 + k) * 27 + cc];
        *(float4*)&Ws[k * 112 + cc * 4] = v;
      }
    }
    __syncthreads();

#pragma unroll
    for (int k4 = 0; k4 < F4C; k4++) {
      float4 w0 = *(const float4*)&Ws[(k4 * 4 + 0) * 112 + coc * 4];
      float4 w1 = *(const float4*)&Ws[(k4 * 4 + 1) * 112 + coc * 4];
      float4 w2 = *(const float4*)&Ws[(k4 * 4 + 2) * 112 + coc * 4];
      float4 w3 = *(const float4*)&Ws[(k4 * 4 + 3) * 112 + coc * 4];
#pragma unroll
      for (int m = 0; m < 8; m++) {
        float4 a = *(const float4*)&As[(nr + m * 8) * AST + k4 * 4];
        acc[m][0] = fmaf(a.x, w0.x, acc[m][0]);
        acc[m][1] = fmaf(a.x, w0.y, acc[m][1]);
        acc[m][2] = fmaf(a.x, w0.z, acc[m][2]);
        acc[m][3] = fmaf(a.x, w0.w, acc[m][3]);
        acc[m][0] = fmaf(a.y, w1.x, acc[m][0]);
        acc[m][1] = fmaf(a.y, w1.y, acc[m][1]);
        acc[m][2] = fmaf(a.y, w1.z, acc[m][2]);
        acc[m][3] = fmaf(a.y, w1.w, acc[m][3]);
        acc[m][0] = fmaf(a.z, w2.x, acc[m][0]);
        acc[m][1] = fmaf(a.z, w2.y, acc[m][1]);
        acc[m][2] = fmaf(a.z, w2.z, acc[m][2]);
        acc[m][3] = fmaf(a.z, w2.w, acc[m][3]);
        acc[m][0] = fmaf(a.w, w3.x, acc[m][0]);
        acc[m][1] = fmaf(a.w, w3.y, acc[m][1]);
        acc[m][2] = fmaf(a.w, w3.z, acc[m][2]);
        acc[m][3] = fmaf(a.w, w3.w, acc[m][3]);
      }
    }
    __syncthreads();
  }

  float4 bias4 = {0.f, 0.f, 0.f, 0.f};
  if (co < 27) bias4 = *(const float4*)&bias[co * 4];
  float4* out4 = (float4*)out;

  if (MODE == 2) {
#pragma unroll 1
    for (int m = 0; m < 8; m++) {
      int gn = n0 + nr + m * 8;
      float b0 = 0.f, b1 = 0.f, b2 = 0.f, b3 = 0.f;
      if (co < 27) {
        b0 = acc[m][0] + bias4.x;
        b1 = acc[m][1] + bias4.y;
        b2 = acc[m][2] + bias4.z;
        b3 = acc[m][3] + bias4.w;
      }
      float ssq = b0 * b0 + b1 * b1 + b2 * b2 + b3 * b3;
#pragma unroll
      for (int s = 1; s < 32; s <<= 1) ssq += __shfl_xor(ssq, s, 32);
      float scale = 1.f / fmaxf(sqrtf(ssq), 1e-12f);
      if (gn < N && co < 27) {
        float4 hv = out4[(size_t)gn * 27 + co];
        float4 r;
        r.x = hv.x + fmaxf(b0 * scale, 0.f);
        r.y = hv.y + fmaxf(b1 * scale, 0.f);
        r.z = hv.z + fmaxf(b2 * scale, 0.f);
        r.w = hv.w + fmaxf(b3 * scale, 0.f);
        out4[(size_t)gn * 27 + co] = r;
      }
    }
  } else if (MODE == 3) {
    __half* outh = (__half*)out;
#pragma unroll 1
    for (int m = 0; m < 8; m++) {
      int gn = n0 + nr + m * 8;
      if (gn < N && co < 27) {
        float r0 = fmaxf(acc[m][0] + bias4.x, 0.f);
        float r1 = fmaxf(acc[m][1] + bias4.y, 0.f);
        float r2 = fmaxf(acc[m][2] + bias4.z, 0.f);
        float r3 = fmaxf(acc[m][3] + bias4.w, 0.f);
        __half2 p0 = __floats2half2_rn(r0, r1);
        __half2 p1 = __floats2half2_rn(r2, r3);
        uint2 pk;
        pk.x = *(unsigned int*)&p0;
        pk.y = *(unsigned int*)&p1;
        *(uint2*)(outh + (size_t)gn * HDIM + co * 4) = pk;
      }
    }
  } else {
#pragma unroll 1
    for (int m = 0; m < 8; m++) {
      int gn = n0 + nr + m * 8;
      if (gn < N && co < 27) {
        float4 r;
        r.x = acc[m][0] + bias4.x;
        r.y = acc[m][1] + bias4.y;
        r.z = acc[m][2] + bias4.z;
        r.w = acc[m][3] + bias4.w;
        out4[(size_t)gn * 27 + co] = r;
      }
    }
  }
}

// ---------------- readout ----------------
__global__ __launch_bounds__(128) void k_cnt_bs(const int* __restrict__ gid, int* __restrict__ cnt, int N) {
  int g = threadIdx.x;
  if (g >= G_GRAPHS) return;
  int lo = 0, hi = N;
  while (lo < hi) { int m = (lo + hi) >> 1; if (gid[m] < g) lo = m + 1; else hi = m; }
  int lb = lo;
  lo = 0; hi = N;
  while (lo < hi) { int m = (lo + hi) >> 1; if (gid[m] <= g) lo = m + 1; else hi = m; }
  cnt[g] = lo - lb;
}

__global__ __launch_bounds__(256) void k_readout(const float* __restrict__ h, const int* __restrict__ gid,
                                                 float* __restrict__ hg, int N) {
  const int CH = 64;
  const int lane = threadIdx.x & 31;
  const int grp = threadIdx.x >> 5;
  int start = (blockIdx.x * 8 + grp) * CH;
  if (start >= N || lane >= 27) return;
  int end = min(start + CH, N);
  const float4* __restrict__ h4 = (const float4*)h;
  float4 acc = {0.f, 0.f, 0.f, 0.f};
  int cur = gid[start];  // sorted graph_ids -> run-length pre-aggregation
  for (int i = start; i < end; i++) {
    int g = gid[i];
    if (g != cur) {
      float* base = &hg[(size_t)cur * HDIM + lane * 4];
      atomicAdd(base + 0, acc.x); atomicAdd(base + 1, acc.y);
      atomicAdd(base + 2, acc.z); atomicAdd(base + 3, acc.w);
      acc.x = acc.y = acc.z = acc.w = 0.f;
      cur = g;
    }
    float4 v = h4[(size_t)i * 27 + lane];
    acc.x += v.x; acc.y += v.y; acc.z += v.z; acc.w += v.w;
  }
  float* base = &hg[(size_t)cur * HDIM + lane * 4];
  atomicAdd(base + 0, acc.x); atomicAdd(base + 1, acc.y);
  atomicAdd(base + 2, acc.z); atomicAdd(base + 3, acc.w);
}

__global__ __launch_bounds__(256) void k_div(const float* __restrict__ hg, const int* __restrict__ cnt,
                                             float* __restrict__ out, int total) {
  int i = blockIdx.x * 256 + threadIdx.x;
  if (i < total) {
    int g = i / HDIM;
    int c = cnt[g];
    out[i] = hg[i] / (float)(c > 0 ? c : 1);
  }
}

// ---------------- launch ----------------
extern "C" void kernel_launch(void* const* d_in, const int* in_sizes, int n_in,
                              void* d_out, int out_size, void* d_ws, size_t ws_size,
                              hipStream_t stream) {
  (void)n_in; (void)ws_size; (void)out_size;
  const float* nodes_feat = (const float*)d_in[0];
  const float* W_emb = (const float*)d_in[4];
  const float* b_emb = (const float*)d_in[5];
  const float* pool_W = (const float*)d_in[6];
  const float* pool_b = (const float*)d_in[7];
  const float* app_W = (const float*)d_in[8];
  const float* app_b = (const float*)d_in[9];
  const int* src = (const int*)d_in[10];
  const int* dst = (const int*)d_in[11];
  const int* gid = (const int*)d_in[12];
  const int N = in_sizes[2];
  const int E = in_sizes[10];
  float* out = (float*)d_out;

  const int nb = (N + 127) >> 7;  // buckets of 128 nodes (<= MAXNB)

  char* ws = (char*)d_ws;
  size_t off = 0;
  auto alloc = [&](size_t bytes) -> size_t {
    size_t o = off;
    off += (bytes + 1023) & ~size_t(1023);
    return o;
  };
  size_t o_gcur = alloc((size_t)MAXNB * 16 * 4);      // 64B-strided bucket counters
  size_t o_cnt  = alloc((size_t)G_GRAPHS * 4);
  size_t o_hg   = alloc((size_t)G_GRAPHS * HDIM * 4);
  size_t zero_bytes = off;  // [gcur, cnt, hg] zeroed in one memset
  size_t o_ebuf = alloc((size_t)MAXNB * CAP * 8);     // bucketized (src,dst) pairs
  size_t o_h = alloc((size_t)N * HDIM * 4);
  size_t o_z = alloc((size_t)N * HDIM * 2);           // fp16 z
  size_t o_c = alloc((size_t)N * HDIM * 4);

  int*    gcur = (int*)(ws + o_gcur);
  int*    cnt  = (int*)(ws + o_cnt);
  float*  hg   = (float*)(ws + o_hg);
  int2*   ebuf = (int2*)(ws + o_ebuf);
  float*  h = (float*)(ws + o_h);
  __half* z = (__half*)(ws + o_z);
  float*  c = (float*)(ws + o_c);

  hipMemsetAsync(d_ws, 0, zero_bytes, stream);

  k_scatter<<<(E + 4095) / 4096, 256, 0, stream>>>(src, dst, gcur, ebuf, E, nb);

  const int nbMM = (N + 63) / 64;
  k_mm<64, 32, 0><<<nbMM, 256, 0, stream>>>(nodes_feat, nullptr, W_emb, b_emb, h, N);

  for (int i = 0; i < 2; i++) {
    k_mm<108, 36, 3><<<nbMM, 256, 0, stream>>>(h, nullptr, pool_W + i * HDIM * HDIM,
                                               pool_b + i * HDIM, (float*)z, N);
    k_bagg<<<nb, 256, 0, stream>>>(z, ebuf, gcur, c, N, nb);
    k_mm<216, 36, 2><<<nbMM, 256, 0, stream>>>(h, c, app_W + i * 2 * HDIM * HDIM,
                                               app_b + i * HDIM, h, N);
  }

  k_cnt_bs<<<1, 128, 0, stream>>>(gid, cnt, N);
  k_readout<<<(N + 8 * 64 - 1) / (8 * 64), 256, 0, stream>>>(h, gid, hg, N);
  k_div<<<(G_GRAPHS * HDIM + 255) / 256, 256, 0, stream>>>(hg, cnt, out, G_GRAPHS * HDIM);
}

// Round 6
// 443.060 us; speedup vs baseline: 3.6195x; 1.5375x over previous
//
#include <hip/hip_runtime.h>

#define HDIM 108
constexpr int G_GRAPHS = 128;
constexpr int MAXNB = 1024;   // max buckets (N up to 131072)
constexpr int CAP = 2560;     // slots per bucket (mean 2048, sigma ~45 -> +11 sigma)

typedef _Float16 half8 __attribute__((ext_vector_type(8)));
typedef _Float16 half4v __attribute__((ext_vector_type(4)));
typedef float floatx4 __attribute__((ext_vector_type(4)));

// ---------------- weight convert: fp32 [K][108] -> fp16 transposed padded [112][Kpad] ----
// split=1 (app): k'<108 -> k', 108..111 -> zero gap, 112..219 -> k'-4, 220..223 -> zero.
__global__ __launch_bounds__(256) void k_cvtw(const float* __restrict__ src, _Float16* __restrict__ dst,
                                              int K, int Kpad, int split) {
  int idx = blockIdx.x * 256 + threadIdx.x;
  int total = 112 * Kpad;
  if (idx >= total) return;
  int n = idx / Kpad, k = idx - n * Kpad;
  int ks;
  if (split) ks = (k < 108) ? k : (k >= 112 && k < 220) ? (k - 4) : -1;
  else       ks = (k < K) ? k : -1;
  float v = (n < 108 && ks >= 0) ? src[ks * 108 + n] : 0.f;
  dst[idx] = (_Float16)v;
}

// ---------------- bucket partition: edges -> (src,dst) pairs grouped by dst>>7 ----------------
__global__ __launch_bounds__(256) void k_scatter(const int* __restrict__ src, const int* __restrict__ dst,
                                                 int* __restrict__ gcur, int2* __restrict__ ebuf,
                                                 int E, int nb) {
  __shared__ int hist[MAXNB];
  const int tid = threadIdx.x;
  const int e0 = blockIdx.x * 4096;
  for (int b = tid; b < nb; b += 256) hist[b] = 0;
  __syncthreads();
#pragma unroll
  for (int it = 0; it < 16; it++) {
    int e = e0 + it * 256 + tid;
    if (e < E) atomicAdd(&hist[dst[e] >> 7], 1);
  }
  __syncthreads();
  for (int b = tid; b < nb; b += 256) {
    int h = hist[b];
    hist[b] = h ? atomicAdd(&gcur[b * 16], h) : 0;
  }
  __syncthreads();
#pragma unroll
  for (int it = 0; it < 16; it++) {
    int e = e0 + it * 256 + tid;
    if (e < E) {
      int d = dst[e];
      int b = d >> 7;
      int rank = atomicAdd(&hist[b], 1);
      if (rank < CAP) ebuf[(size_t)b * CAP + rank] = make_int2(src[e], d);
    }
  }
}

// ---------------- bucket aggregation: c16[v] = mean_{e: dst==v} z16[src[e]] ----------------
__global__ __launch_bounds__(256) void k_bagg(const _Float16* __restrict__ z, const int2* __restrict__ ebuf,
                                              const int* __restrict__ gcur, _Float16* __restrict__ c16,
                                              int N, int nb) {
  __shared__ int cnts[128];
  __shared__ int scanb[128];
  __shared__ int off[129];
  __shared__ int ecur[128];
  __shared__ int esrc[CAP];
  const int tid = threadIdx.x;
  const int b = blockIdx.x;
  const int v0 = b << 7;
  int cntb = gcur[b * 16];
  if (cntb > CAP) cntb = CAP;
  const int2* eb = ebuf + (size_t)b * CAP;

  if (tid < 128) cnts[tid] = 0;
  __syncthreads();
  for (int i = tid; i < cntb; i += 256) atomicAdd(&cnts[eb[i].y & 127], 1);
  __syncthreads();
  if (tid < 128) scanb[tid] = cnts[tid];
  __syncthreads();
#pragma unroll
  for (int st = 1; st < 128; st <<= 1) {
    int v = 0;
    if (tid < 128 && tid >= st) v = scanb[tid - st];
    __syncthreads();
    if (tid < 128) scanb[tid] += v;
    __syncthreads();
  }
  if (tid == 0) off[0] = 0;
  if (tid < 128) {
    off[tid + 1] = scanb[tid];
    ecur[tid] = scanb[tid] - cnts[tid];
  }
  __syncthreads();
  for (int i = tid; i < cntb; i += 256) {
    int2 e = eb[i];
    int p = atomicAdd(&ecur[e.y & 127], 1);
    esrc[p] = e.x;
  }
  __syncthreads();

  const int lane = tid & 31;
  const int grp = tid >> 5;                 // 8 groups of 32
  const int lc = (lane < 27) ? lane : 26;
#pragma unroll 1
  for (int r = grp; r < 128; r += 8) {
    int v = v0 + r;
    if (v >= N) continue;
    int s = off[r], e2 = off[r + 1];
    float a0 = 0.f, a1 = 0.f, a2 = 0.f, a3 = 0.f;
    int j = s;
    for (; j + 2 <= e2; j += 2) {
      int s0 = esrc[j], s1 = esrc[j + 1];
      half4v q0 = *(const half4v*)(z + (size_t)s0 * 112 + lc * 4);
      half4v q1 = *(const half4v*)(z + (size_t)s1 * 112 + lc * 4);
      a0 += (float)q0[0] + (float)q1[0];
      a1 += (float)q0[1] + (float)q1[1];
      a2 += (float)q0[2] + (float)q1[2];
      a3 += (float)q0[3] + (float)q1[3];
    }
    if (j < e2) {
      half4v q0 = *(const half4v*)(z + (size_t)esrc[j] * 112 + lc * 4);
      a0 += (float)q0[0]; a1 += (float)q0[1]; a2 += (float)q0[2]; a3 += (float)q0[3];
    }
    int d = e2 - s;
    float inv = 1.f / (float)(d > 0 ? d : 1);
    if (lane < 27) {
      half4v r4;
      r4[0] = (_Float16)(a0 * inv); r4[1] = (_Float16)(a1 * inv);
      r4[2] = (_Float16)(a2 * inv); r4[3] = (_Float16)(a3 * inv);
      *(half4v*)(c16 + (size_t)v * 112 + lane * 4) = r4;
    } else if (lane == 27) {
      half4v zz = {0, 0, 0, 0};
      *(half4v*)(c16 + (size_t)v * 112 + 108) = zz;  // keep pad cols 108..111 zero
    }
  }
}

// ---------------- MFMA GEMM: out[N,108] = A[N,K'] @ W'[K',108] (+bias, act) ----------------
// fp16 inputs, fp32 accumulate via v_mfma_f32_16x16x32_f16.
// Block 256 = 4 waves; tile 128 rows x 112 cols. Wave: 32 rows = 2 row-tiles x 7 col-tiles.
// K' padded to KCH*32; Wt is [112][KCH*32] (transposed, zero-padded, app: gap-remapped).
// LDS rows padded to 40 halves -> conflict-free ds_read_b128 fragments.
// Wt cols >=108 are zero => acc at invalid cols is exactly 0 (no col guards needed).
// MODE 0: emb (A = fp32 feat [N][64], converted in staging; +bias; writes h16 incl. zero pad).
// MODE 1: pool (+bias, ReLU -> z16).
// MODE 2: app (A' = [h16 | gap | c16]; +bias -> row L2 norm -> ReLU -> residual into h16).
template <int KCH, int MODE>
__global__ __launch_bounds__(256, 2) void k_mmf(const void* Asrc, const _Float16* __restrict__ c16,
                                                const _Float16* __restrict__ Wt, const float* __restrict__ bias,
                                                _Float16* __restrict__ out16, int N) {
  constexpr int KW = KCH * 32;
  __shared__ _Float16 As[128 * 40];
  __shared__ _Float16 Ws[112 * 40];

  const int tid = threadIdx.x;
  const int wave = tid >> 6;
  const int lane = tid & 63;
  const int lo = lane & 15;
  const int quad = lane >> 4;
  const int n0 = blockIdx.x * 128;
  const _Float16* h16 = (const _Float16*)Asrc;
  const float* feat = (const float*)Asrc;

  floatx4 acc[2][7];
#pragma unroll
  for (int rt = 0; rt < 2; rt++)
#pragma unroll
    for (int ct = 0; ct < 7; ct++) {
      floatx4 zz = {0.f, 0.f, 0.f, 0.f};
      acc[rt][ct] = zz;
    }

#pragma unroll 1
  for (int kc = 0; kc < KCH; kc++) {
    // ---- stage A chunk: 128 rows x 32 halves (4 segs of 8) ----
#pragma unroll
    for (int it = 0; it < 2; it++) {
      int idx = tid + it * 256;
      int r = idx >> 2, sg = idx & 3;
      int gn = n0 + r;
      int k = kc * 32 + sg * 8;
      half8 v = {0, 0, 0, 0, 0, 0, 0, 0};
      if (gn < N) {
        if (MODE == 0) {
          float4 f0 = *(const float4*)(feat + (size_t)gn * 64 + k);
          float4 f1 = *(const float4*)(feat + (size_t)gn * 64 + k + 4);
          v[0] = (_Float16)f0.x; v[1] = (_Float16)f0.y; v[2] = (_Float16)f0.z; v[3] = (_Float16)f0.w;
          v[4] = (_Float16)f1.x; v[5] = (_Float16)f1.y; v[6] = (_Float16)f1.z; v[7] = (_Float16)f1.w;
        } else if (MODE == 2) {
          const _Float16* sp = (k < 112) ? (h16 + (size_t)gn * 112 + k)
                                         : (c16 + (size_t)gn * 112 + (k - 112));
          v = *(const half8*)sp;
        } else {  // MODE 1: K'=128, cols 112..127 are zero
          if (k < 112) v = *(const half8*)(h16 + (size_t)gn * 112 + k);
        }
      }
      *(half8*)&As[r * 40 + sg * 8] = v;
    }
    // ---- stage W chunk: 112 rows x 32 halves ----
#pragma unroll
    for (int it = 0; it < 2; it++) {
      int idx = tid + it * 256;
      if (idx < 112 * 4) {
        int nrow = idx >> 2, sg = idx & 3;
        half8 v = *(const half8*)(Wt + (size_t)nrow * KW + kc * 32 + sg * 8);
        *(half8*)&Ws[nrow * 40 + sg * 8] = v;
      }
    }
    __syncthreads();

    // ---- MFMA: 2 row-tiles x 7 col-tiles ----
    half8 a0 = *(const half8*)&As[(wave * 32 + lo) * 40 + quad * 8];
    half8 a1 = *(const half8*)&As[(wave * 32 + 16 + lo) * 40 + quad * 8];
#pragma unroll
    for (int ct = 0; ct < 7; ct++) {
      half8 b = *(const half8*)&Ws[(ct * 16 + lo) * 40 + quad * 8];
      acc[0][ct] = __builtin_amdgcn_mfma_f32_16x16x32_f16(a0, b, acc[0][ct], 0, 0, 0);
      acc[1][ct] = __builtin_amdgcn_mfma_f32_16x16x32_f16(a1, b, acc[1][ct], 0, 0, 0);
    }
    __syncthreads();
  }

  // ---- epilogue (C/D layout: col = ct*16+lo, row = quad*4+reg within tile) ----
  float bias_v[7];
#pragma unroll
  for (int ct = 0; ct < 7; ct++) {
    int col = ct * 16 + lo;
    bias_v[ct] = (col < 108) ? bias[col] : 0.f;
  }

  if (MODE == 2) {
#pragma unroll
    for (int rt = 0; rt < 2; rt++) {
#pragma unroll
      for (int reg = 0; reg < 4; reg++) {
        int gr = n0 + wave * 32 + rt * 16 + quad * 4 + reg;
        float bv[7];
        float ssq = 0.f;
#pragma unroll
        for (int ct = 0; ct < 7; ct++) {
          float t = acc[rt][ct][reg] + bias_v[ct];  // == 0 at pad cols (W,bias zero)
          bv[ct] = t;
          ssq += t * t;
        }
#pragma unroll
        for (int s = 1; s < 16; s <<= 1) ssq += __shfl_xor(ssq, s, 16);
        float scale = 1.f / fmaxf(sqrtf(ssq), 1e-12f);
        if (gr < N) {
          _Float16* hp = out16 + (size_t)gr * 112 + lo;
#pragma unroll
          for (int ct = 0; ct < 7; ct++) {
            float hv = (float)hp[ct * 16];
            hp[ct * 16] = (_Float16)(hv + fmaxf(bv[ct] * scale, 0.f));
          }
        }
      }
    }
  } else {
#pragma unroll
    for (int rt = 0; rt < 2; rt++) {
#pragma unroll
      for (int reg = 0; reg < 4; reg++) {
        int gr = n0 + wave * 32 + rt * 16 + quad * 4 + reg;
        if (gr < N) {
          _Float16* op = out16 + (size_t)gr * 112 + lo;
#pragma unroll
          for (int ct = 0; ct < 7; ct++) {
            float t = acc[rt][ct][reg] + bias_v[ct];
            if (MODE == 1) t = fmaxf(t, 0.f);
            op[ct * 16] = (_Float16)t;  // pad cols get 0 (emb keeps h16 pad zero)
          }
        }
      }
    }
  }
}

// ---------------- readout ----------------
__global__ __launch_bounds__(128) void k_cnt_bs(const int* __restrict__ gid, int* __restrict__ cnt, int N) {
  int g = threadIdx.x;
  if (g >= G_GRAPHS) return;
  int lo = 0, hi = N;
  while (lo < hi) { int m = (lo + hi) >> 1; if (gid[m] < g) lo = m + 1; else hi = m; }
  int lb = lo;
  lo = 0; hi = N;
  while (lo < hi) { int m = (lo + hi) >> 1; if (gid[m] <= g) lo = m + 1; else hi = m; }
  cnt[g] = lo - lb;
}

__global__ __launch_bounds__(256) void k_readout(const _Float16* __restrict__ h, const int* __restrict__ gid,
                                                 float* __restrict__ hg, int N) {
  const int CH = 64;
  const int lane = threadIdx.x & 31;
  const int grp = threadIdx.x >> 5;
  int start = (blockIdx.x * 8 + grp) * CH;
  if (start >= N || lane >= 27) return;
  int end = min(start + CH, N);
  float a0 = 0.f, a1 = 0.f, a2 = 0.f, a3 = 0.f;
  int cur = gid[start];  // sorted graph_ids -> run-length pre-aggregation
  for (int i = start; i < end; i++) {
    int g = gid[i];
    if (g != cur) {
      float* base = &hg[(size_t)cur * HDIM + lane * 4];
      atomicAdd(base + 0, a0); atomicAdd(base + 1, a1);
      atomicAdd(base + 2, a2); atomicAdd(base + 3, a3);
      a0 = a1 = a2 = a3 = 0.f;
      cur = g;
    }
    half4v v = *(const half4v*)(h + (size_t)i * 112 + lane * 4);
    a0 += (float)v[0]; a1 += (float)v[1]; a2 += (float)v[2]; a3 += (float)v[3];
  }
  float* base = &hg[(size_t)cur * HDIM + lane * 4];
  atomicAdd(base + 0, a0); atomicAdd(base + 1, a1);
  atomicAdd(base + 2, a2); atomicAdd(base + 3, a3);
}

__global__ __launch_bounds__(256) void k_div(const float* __restrict__ hg, const int* __restrict__ cnt,
                                             float* __restrict__ out, int total) {
  int i = blockIdx.x * 256 + threadIdx.x;
  if (i < total) {
    int g = i / HDIM;
    int c = cnt[g];
    out[i] = hg[i] / (float)(c > 0 ? c : 1);
  }
}

// ---------------- launch ----------------
extern "C" void kernel_launch(void* const* d_in, const int* in_sizes, int n_in,
                              void* d_out, int out_size, void* d_ws, size_t ws_size,
                              hipStream_t stream) {
  (void)n_in; (void)ws_size; (void)out_size;
  const float* nodes_feat = (const float*)d_in[0];
  const float* W_emb = (const float*)d_in[4];
  const float* b_emb = (const float*)d_in[5];
  const float* pool_W = (const float*)d_in[6];
  const float* pool_b = (const float*)d_in[7];
  const float* app_W = (const float*)d_in[8];
  const float* app_b = (const float*)d_in[9];
  const int* src = (const int*)d_in[10];
  const int* dst = (const int*)d_in[11];
  const int* gid = (const int*)d_in[12];
  const int N = in_sizes[2];
  const int E = in_sizes[10];
  float* out = (float*)d_out;

  const int nb = (N + 127) >> 7;

  char* ws = (char*)d_ws;
  size_t off = 0;
  auto alloc = [&](size_t bytes) -> size_t {
    size_t o = off;
    off += (bytes + 1023) & ~size_t(1023);
    return o;
  };
  size_t o_gcur = alloc((size_t)MAXNB * 16 * 4);
  size_t o_cnt  = alloc((size_t)G_GRAPHS * 4);
  size_t o_hg   = alloc((size_t)G_GRAPHS * HDIM * 4);
  size_t zero_bytes = off;  // [gcur, cnt, hg]
  size_t o_ebuf = alloc((size_t)MAXNB * CAP * 8);
  size_t o_h  = alloc((size_t)N * 112 * 2);
  size_t o_z  = alloc((size_t)N * 112 * 2);
  size_t o_c  = alloc((size_t)N * 112 * 2);
  size_t o_we = alloc((size_t)112 * 64 * 2);
  size_t o_wp = alloc((size_t)2 * 112 * 128 * 2);
  size_t o_wa = alloc((size_t)2 * 112 * 224 * 2);

  int*      gcur = (int*)(ws + o_gcur);
  int*      cnt  = (int*)(ws + o_cnt);
  float*    hg   = (float*)(ws + o_hg);
  int2*     ebuf = (int2*)(ws + o_ebuf);
  _Float16* h16  = (_Float16*)(ws + o_h);
  _Float16* z16  = (_Float16*)(ws + o_z);
  _Float16* c16  = (_Float16*)(ws + o_c);
  _Float16* wte  = (_Float16*)(ws + o_we);
  _Float16* wtp  = (_Float16*)(ws + o_wp);
  _Float16* wta  = (_Float16*)(ws + o_wa);

  hipMemsetAsync(d_ws, 0, zero_bytes, stream);

  k_cvtw<<<(112 * 64 + 255) / 256, 256, 0, stream>>>(W_emb, wte, 64, 64, 0);
  k_cvtw<<<(112 * 128 + 255) / 256, 256, 0, stream>>>(pool_W, wtp, 108, 128, 0);
  k_cvtw<<<(112 * 128 + 255) / 256, 256, 0, stream>>>(pool_W + 11664, wtp + 112 * 128, 108, 128, 0);
  k_cvtw<<<(112 * 224 + 255) / 256, 256, 0, stream>>>(app_W, wta, 216, 224, 1);
  k_cvtw<<<(112 * 224 + 255) / 256, 256, 0, stream>>>(app_W + 23328, wta + 112 * 224, 216, 224, 1);

  k_scatter<<<(E + 4095) / 4096, 256, 0, stream>>>(src, dst, gcur, ebuf, E, nb);

  const int nbMM = (N + 127) / 128;
  k_mmf<2, 0><<<nbMM, 256, 0, stream>>>(nodes_feat, nullptr, wte, b_emb, h16, N);

  for (int i = 0; i < 2; i++) {
    k_mmf<4, 1><<<nbMM, 256, 0, stream>>>(h16, nullptr, wtp + i * 112 * 128,
                                          pool_b + i * HDIM, z16, N);
    k_bagg<<<nb, 256, 0, stream>>>(z16, ebuf, gcur, c16, N, nb);
    k_mmf<7, 2><<<nbMM, 256, 0, stream>>>(h16, c16, wta + i * 112 * 224,
                                          app_b + i * HDIM, h16, N);
  }

  k_cnt_bs<<<1, 128, 0, stream>>>(gid, cnt, N);
  k_readout<<<(N + 8 * 64 - 1) / (8 * 64), 256, 0, stream>>>(h16, gid, hg, N);
  k_div<<<(G_GRAPHS * HDIM + 255) / 256, 256, 0, stream>>>(hg, cnt, out, G_GRAPHS * HDIM);
}

// Round 8
// 426.110 us; speedup vs baseline: 3.7635x; 1.0398x over previous
//
#include <hip/hip_runtime.h>

#define HDIM 108
constexpr int G_GRAPHS = 128;
constexpr int MAXNB = 1024;   // max buckets (N up to 131072)
constexpr int CAP = 2560;     // slots per bucket (mean 2048, sigma ~45 -> +11 sigma)

typedef _Float16 half8 __attribute__((ext_vector_type(8)));
typedef _Float16 half4v __attribute__((ext_vector_type(4)));
typedef float floatx4 __attribute__((ext_vector_type(4)));
typedef float floatx2 __attribute__((ext_vector_type(2)));

// ---------------- fp8 e4m3 helpers (OCP on gfx950) ----------------
__device__ inline unsigned char f32_to_fp8(float t) {
#if __has_builtin(__builtin_amdgcn_cvt_pk_fp8_f32)
  return (unsigned char)(__builtin_amdgcn_cvt_pk_fp8_f32(t, t, 0, false) & 0xFF);
#else
  // manual e4m3fn RNE (t >= 0 post-relu)
  t = fminf(t, 448.f);
  if (t < 0.015625f) return (unsigned char)__float2int_rn(t * 512.f);
  unsigned u = __float_as_uint(t);
  unsigned lsb = (u >> 20) & 1;
  u += 0x7FFFFu + lsb;
  int e = (int)((u >> 23) & 0xFF) - 127;
  if (e > 8) return 0x7E;
  return (unsigned char)(((e + 7) << 3) | ((u >> 20) & 7));
#endif
}

template <bool HI>
__device__ inline floatx2 fp8x2_to_f32(unsigned v) {
#if __has_builtin(__builtin_amdgcn_cvt_pk_f32_fp8)
  return __builtin_amdgcn_cvt_pk_f32_fp8((int)v, HI);
#else
  unsigned b0 = HI ? ((v >> 16) & 0xFF) : (v & 0xFF);
  unsigned b1 = HI ? ((v >> 24) & 0xFF) : ((v >> 8) & 0xFF);
  floatx2 r;
  {
    unsigned s = b0 >> 7, e = (b0 >> 3) & 0xF, m = b0 & 7;
    float f = (e == 0) ? (float)m * 0.001953125f
                       : __uint_as_float(((e + 120u) << 23) | (m << 20));
    r[0] = s ? -f : f;
  }
  {
    unsigned s = b1 >> 7, e = (b1 >> 3) & 0xF, m = b1 & 7;
    float f = (e == 0) ? (float)m * 0.001953125f
                       : __uint_as_float(((e + 120u) << 23) | (m << 20));
    r[1] = s ? -f : f;
  }
  return r;
#endif
}

// ---------------- weight convert: fp32 [K][108] -> fp16 transposed padded [112][Kpad] ----
__global__ __launch_bounds__(256) void k_cvtw(const float* __restrict__ src, _Float16* __restrict__ dst,
                                              int K, int Kpad, int split) {
  int idx = blockIdx.x * 256 + threadIdx.x;
  int total = 112 * Kpad;
  if (idx >= total) return;
  int n = idx / Kpad, k = idx - n * Kpad;
  int ks;
  if (split) ks = (k < 108) ? k : (k >= 112 && k < 220) ? (k - 4) : -1;
  else       ks = (k < K) ? k : -1;
  float v = (n < 108 && ks >= 0) ? src[ks * 108 + n] : 0.f;
  dst[idx] = (_Float16)v;
}

// ---------------- bucket partition: edges -> packed (src | ld<<20) grouped by dst>>7 --------
__global__ __launch_bounds__(256) void k_scatter(const int* __restrict__ src, const int* __restrict__ dst,
                                                 int* __restrict__ gcur, int* __restrict__ ebuf,
                                                 int E, int nb) {
  __shared__ int hist[MAXNB];
  const int tid = threadIdx.x;
  const int e0 = blockIdx.x * 4096;
  for (int b = tid; b < nb; b += 256) hist[b] = 0;
  __syncthreads();
#pragma unroll
  for (int it = 0; it < 16; it++) {
    int e = e0 + it * 256 + tid;
    if (e < E) atomicAdd(&hist[dst[e] >> 7], 1);
  }
  __syncthreads();
  for (int b = tid; b < nb; b += 256) {
    int h = hist[b];
    hist[b] = h ? atomicAdd(&gcur[b * 16], h) : 0;
  }
  __syncthreads();
#pragma unroll
  for (int it = 0; it < 16; it++) {
    int e = e0 + it * 256 + tid;
    if (e < E) {
      int d = dst[e];
      int b = d >> 7;
      int rank = atomicAdd(&hist[b], 1);
      if (rank < CAP) ebuf[(size_t)b * CAP + rank] = src[e] | ((d & 127) << 20);
    }
  }
}

// ---------------- bucket aggregation: c16[v] = mean_{e: dst==v} fp8 z[src[e]] ---------------
// One block per bucket (128 nodes). LDS counting-sort by local dst, then 32-lane groups
// (28 active: 4 fp8 cols each) gather 112-B fp8 z rows, decode via v_cvt_pk_f32_fp8,
// accumulate fp32, write fp16 c (cols 108..111 decode from zero pad -> c pad stays 0).
__global__ __launch_bounds__(256) void k_bagg(const unsigned char* __restrict__ z, const int* __restrict__ ebuf,
                                              const int* __restrict__ gcur, _Float16* __restrict__ c16,
                                              int N, int nb) {
  __shared__ int cnts[128];
  __shared__ int scanb[128];
  __shared__ int off[129];
  __shared__ int ecur[128];
  __shared__ int esrc[CAP];
  const int tid = threadIdx.x;
  const int b = blockIdx.x;
  const int v0 = b << 7;
  int cntb = gcur[b * 16];
  if (cntb > CAP) cntb = CAP;
  const int* eb = ebuf + (size_t)b * CAP;

  if (tid < 128) cnts[tid] = 0;
  __syncthreads();
  for (int i = tid; i < cntb; i += 256) atomicAdd(&cnts[eb[i] >> 20], 1);
  __syncthreads();
  if (tid < 128) scanb[tid] = cnts[tid];
  __syncthreads();
#pragma unroll
  for (int st = 1; st < 128; st <<= 1) {
    int v = 0;
    if (tid < 128 && tid >= st) v = scanb[tid - st];
    __syncthreads();
    if (tid < 128) scanb[tid] += v;
    __syncthreads();
  }
  if (tid == 0) off[0] = 0;
  if (tid < 128) {
    off[tid + 1] = scanb[tid];
    ecur[tid] = scanb[tid] - cnts[tid];
  }
  __syncthreads();
  for (int i = tid; i < cntb; i += 256) {
    int e = eb[i];
    int p = atomicAdd(&ecur[e >> 20], 1);
    esrc[p] = e & 0xFFFFF;
  }
  __syncthreads();

  const int lane = tid & 31;
  const int grp = tid >> 5;                 // 8 groups of 32 (28 active)
  if (lane >= 28) return;
#pragma unroll 1
  for (int r = grp; r < 128; r += 8) {
    int v = v0 + r;
    if (v >= N) continue;
    int s = off[r], e2 = off[r + 1];
    float a0 = 0.f, a1 = 0.f, a2 = 0.f, a3 = 0.f;
    int j = s;
    for (; j + 2 <= e2; j += 2) {
      int s0 = esrc[j], s1 = esrc[j + 1];
      unsigned q0 = *(const unsigned*)(z + (size_t)s0 * 112 + lane * 4);
      unsigned q1 = *(const unsigned*)(z + (size_t)s1 * 112 + lane * 4);
      floatx2 l0 = fp8x2_to_f32<false>(q0), h0 = fp8x2_to_f32<true>(q0);
      floatx2 l1 = fp8x2_to_f32<false>(q1), h1 = fp8x2_to_f32<true>(q1);
      a0 += l0[0] + l1[0]; a1 += l0[1] + l1[1];
      a2 += h0[0] + h1[0]; a3 += h0[1] + h1[1];
    }
    if (j < e2) {
      unsigned q0 = *(const unsigned*)(z + (size_t)esrc[j] * 112 + lane * 4);
      floatx2 l0 = fp8x2_to_f32<false>(q0), h0 = fp8x2_to_f32<true>(q0);
      a0 += l0[0]; a1 += l0[1]; a2 += h0[0]; a3 += h0[1];
    }
    int d = e2 - s;
    float inv = 1.f / (float)(d > 0 ? d : 1);
    half4v r4;
    r4[0] = (_Float16)(a0 * inv); r4[1] = (_Float16)(a1 * inv);
    r4[2] = (_Float16)(a2 * inv); r4[3] = (_Float16)(a3 * inv);
    *(half4v*)(c16 + (size_t)v * 112 + lane * 4) = r4;
  }
}

// ---------------- MFMA GEMM: out[N,108] = A[N,K'] @ W'[K',108] (+bias, act) ----------------
// MODE 0: emb (fp32 feat in, +bias -> h16). MODE 1: pool (+bias, ReLU -> fp8 z).
// MODE 2: app ([h16|gap|c16]; +bias -> row L2 norm -> ReLU -> residual into h16).
template <int KCH, int MODE>
__global__ __launch_bounds__(256, 2) void k_mmf(const void* Asrc, const _Float16* __restrict__ c16,
                                                const _Float16* __restrict__ Wt, const float* __restrict__ bias,
                                                void* outp, int N) {
  constexpr int KW = KCH * 32;
  __shared__ _Float16 As[128 * 40];
  __shared__ _Float16 Ws[112 * 40];

  const int tid = threadIdx.x;
  const int wave = tid >> 6;
  const int lane = tid & 63;
  const int lo = lane & 15;
  const int quad = lane >> 4;
  const int n0 = blockIdx.x * 128;
  const _Float16* h16 = (const _Float16*)Asrc;
  const float* feat = (const float*)Asrc;

  floatx4 acc[2][7];
#pragma unroll
  for (int rt = 0; rt < 2; rt++)
#pragma unroll
    for (int ct = 0; ct < 7; ct++) {
      floatx4 zz = {0.f, 0.f, 0.f, 0.f};
      acc[rt][ct] = zz;
    }

#pragma unroll 1
  for (int kc = 0; kc < KCH; kc++) {
#pragma unroll
    for (int it = 0; it < 2; it++) {
      int idx = tid + it * 256;
      int r = idx >> 2, sg = idx & 3;
      int gn = n0 + r;
      int k = kc * 32 + sg * 8;
      half8 v = {0, 0, 0, 0, 0, 0, 0, 0};
      if (gn < N) {
        if (MODE == 0) {
          float4 f0 = *(const float4*)(feat + (size_t)gn * 64 + k);
          float4 f1 = *(const float4*)(feat + (size_t)gn * 64 + k + 4);
          v[0] = (_Float16)f0.x; v[1] = (_Float16)f0.y; v[2] = (_Float16)f0.z; v[3] = (_Float16)f0.w;
          v[4] = (_Float16)f1.x; v[5] = (_Float16)f1.y; v[6] = (_Float16)f1.z; v[7] = (_Float16)f1.w;
        } else if (MODE == 2) {
          const _Float16* sp = (k < 112) ? (h16 + (size_t)gn * 112 + k)
                                         : (c16 + (size_t)gn * 112 + (k - 112));
          v = *(const half8*)sp;
        } else {  // MODE 1: K'=128, cols 112..127 are zero
          if (k < 112) v = *(const half8*)(h16 + (size_t)gn * 112 + k);
        }
      }
      *(half8*)&As[r * 40 + sg * 8] = v;
    }
#pragma unroll
    for (int it = 0; it < 2; it++) {
      int idx = tid + it * 256;
      if (idx < 112 * 4) {
        int nrow = idx >> 2, sg = idx & 3;
        half8 v = *(const half8*)(Wt + (size_t)nrow * KW + kc * 32 + sg * 8);
        *(half8*)&Ws[nrow * 40 + sg * 8] = v;
      }
    }
    __syncthreads();

    half8 a0 = *(const half8*)&As[(wave * 32 + lo) * 40 + quad * 8];
    half8 a1 = *(const half8*)&As[(wave * 32 + 16 + lo) * 40 + quad * 8];
#pragma unroll
    for (int ct = 0; ct < 7; ct++) {
      half8 b = *(const half8*)&Ws[(ct * 16 + lo) * 40 + quad * 8];
      acc[0][ct] = __builtin_amdgcn_mfma_f32_16x16x32_f16(a0, b, acc[0][ct], 0, 0, 0);
      acc[1][ct] = __builtin_amdgcn_mfma_f32_16x16x32_f16(a1, b, acc[1][ct], 0, 0, 0);
    }
    __syncthreads();
  }

  float bias_v[7];
#pragma unroll
  for (int ct = 0; ct < 7; ct++) {
    int col = ct * 16 + lo;
    bias_v[ct] = (col < 108) ? bias[col] : 0.f;
  }

  if (MODE == 2) {
    _Float16* out16 = (_Float16*)outp;
#pragma unroll
    for (int rt = 0; rt < 2; rt++) {
#pragma unroll
      for (int reg = 0; reg < 4; reg++) {
        int gr = n0 + wave * 32 + rt * 16 + quad * 4 + reg;
        float bv[7];
        float ssq = 0.f;
#pragma unroll
        for (int ct = 0; ct < 7; ct++) {
          float t = acc[rt][ct][reg] + bias_v[ct];  // == 0 at pad cols
          bv[ct] = t;
          ssq += t * t;
        }
#pragma unroll
        for (int s = 1; s < 16; s <<= 1) ssq += __shfl_xor(ssq, s, 16);
        float scale = 1.f / fmaxf(sqrtf(ssq), 1e-12f);
        if (gr < N) {
          _Float16* hp = out16 + (size_t)gr * 112 + lo;
#pragma unroll
          for (int ct = 0; ct < 7; ct++) {
            float hv = (float)hp[ct * 16];
            hp[ct * 16] = (_Float16)(hv + fmaxf(bv[ct] * scale, 0.f));
          }
        }
      }
    }
  } else if (MODE == 1) {
    unsigned char* outb = (unsigned char*)outp;
#pragma unroll
    for (int rt = 0; rt < 2; rt++) {
#pragma unroll
      for (int reg = 0; reg < 4; reg++) {
        int gr = n0 + wave * 32 + rt * 16 + quad * 4 + reg;
        if (gr < N) {
          unsigned char* op = outb + (size_t)gr * 112 + lo;
#pragma unroll
          for (int ct = 0; ct < 7; ct++) {
            float t = fmaxf(acc[rt][ct][reg] + bias_v[ct], 0.f);  // pad cols -> 0
            op[ct * 16] = f32_to_fp8(t);
          }
        }
      }
    }
  } else {
    _Float16* out16 = (_Float16*)outp;
#pragma unroll
    for (int rt = 0; rt < 2; rt++) {
#pragma unroll
      for (int reg = 0; reg < 4; reg++) {
        int gr = n0 + wave * 32 + rt * 16 + quad * 4 + reg;
        if (gr < N) {
          _Float16* op = out16 + (size_t)gr * 112 + lo;
#pragma unroll
          for (int ct = 0; ct < 7; ct++) {
            float t = acc[rt][ct][reg] + bias_v[ct];
            op[ct * 16] = (_Float16)t;  // pad cols get 0
          }
        }
      }
    }
  }
}

// ---------------- readout ----------------
__global__ __launch_bounds__(128) void k_cnt_bs(const int* __restrict__ gid, int* __restrict__ cnt, int N) {
  int g = threadIdx.x;
  if (g >= G_GRAPHS) return;
  int lo = 0, hi = N;
  while (lo < hi) { int m = (lo + hi) >> 1; if (gid[m] < g) lo = m + 1; else hi = m; }
  int lb = lo;
  lo = 0; hi = N;
  while (lo < hi) { int m = (lo + hi) >> 1; if (gid[m] <= g) lo = m + 1; else hi = m; }
  cnt[g] = lo - lb;
}

__global__ __launch_bounds__(256) void k_readout(const _Float16* __restrict__ h, const int* __restrict__ gid,
                                                 float* __restrict__ hg, int N) {
  const int CH = 64;
  const int lane = threadIdx.x & 31;
  const int grp = threadIdx.x >> 5;
  int start = (blockIdx.x * 8 + grp) * CH;
  if (start >= N || lane >= 27) return;
  int end = min(start + CH, N);
  float a0 = 0.f, a1 = 0.f, a2 = 0.f, a3 = 0.f;
  int cur = gid[start];  // sorted graph_ids -> run-length pre-aggregation
  for (int i = start; i < end; i++) {
    int g = gid[i];
    if (g != cur) {
      float* base = &hg[(size_t)cur * HDIM + lane * 4];
      atomicAdd(base + 0, a0); atomicAdd(base + 1, a1);
      atomicAdd(base + 2, a2); atomicAdd(base + 3, a3);
      a0 = a1 = a2 = a3 = 0.f;
      cur = g;
    }
    half4v v = *(const half4v*)(h + (size_t)i * 112 + lane * 4);
    a0 += (float)v[0]; a1 += (float)v[1]; a2 += (float)v[2]; a3 += (float)v[3];
  }
  float* base = &hg[(size_t)cur * HDIM + lane * 4];
  atomicAdd(base + 0, a0); atomicAdd(base + 1, a1);
  atomicAdd(base + 2, a2); atomicAdd(base + 3, a3);
}

__global__ __launch_bounds__(256) void k_div(const float* __restrict__ hg, const int* __restrict__ cnt,
                                             float* __restrict__ out, int total) {
  int i = blockIdx.x * 256 + threadIdx.x;
  if (i < total) {
    int g = i / HDIM;
    int c = cnt[g];
    out[i] = hg[i] / (float)(c > 0 ? c : 1);
  }
}

// ---------------- launch ----------------
extern "C" void kernel_launch(void* const* d_in, const int* in_sizes, int n_in,
                              void* d_out, int out_size, void* d_ws, size_t ws_size,
                              hipStream_t stream) {
  (void)n_in; (void)ws_size; (void)out_size;
  const float* nodes_feat = (const float*)d_in[0];
  const float* W_emb = (const float*)d_in[4];
  const float* b_emb = (const float*)d_in[5];
  const float* pool_W = (const float*)d_in[6];
  const float* pool_b = (const float*)d_in[7];
  const float* app_W = (const float*)d_in[8];
  const float* app_b = (const float*)d_in[9];
  const int* src = (const int*)d_in[10];
  const int* dst = (const int*)d_in[11];
  const int* gid = (const int*)d_in[12];
  const int N = in_sizes[2];
  const int E = in_sizes[10];
  float* out = (float*)d_out;

  const int nb = (N + 127) >> 7;

  char* ws = (char*)d_ws;
  size_t off = 0;
  auto alloc = [&](size_t bytes) -> size_t {
    size_t o = off;
    off += (bytes + 1023) & ~size_t(1023);
    return o;
  };
  size_t o_gcur = alloc((size_t)MAXNB * 16 * 4);
  size_t o_cnt  = alloc((size_t)G_GRAPHS * 4);
  size_t o_hg   = alloc((size_t)G_GRAPHS * HDIM * 4);
  size_t zero_bytes = off;  // [gcur, cnt, hg]
  size_t o_ebuf = alloc((size_t)MAXNB * CAP * 4);     // packed src|ld<<20
  size_t o_h  = alloc((size_t)N * 112 * 2);
  size_t o_z  = alloc((size_t)N * 112);               // fp8 z
  size_t o_c  = alloc((size_t)N * 112 * 2);
  size_t o_we = alloc((size_t)112 * 64 * 2);
  size_t o_wp = alloc((size_t)2 * 112 * 128 * 2);
  size_t o_wa = alloc((size_t)2 * 112 * 224 * 2);

  int*           gcur = (int*)(ws + o_gcur);
  int*           cnt  = (int*)(ws + o_cnt);
  float*         hg   = (float*)(ws + o_hg);
  int*           ebuf = (int*)(ws + o_ebuf);
  _Float16*      h16  = (_Float16*)(ws + o_h);
  unsigned char* z8   = (unsigned char*)(ws + o_z);
  _Float16*      c16  = (_Float16*)(ws + o_c);
  _Float16*      wte  = (_Float16*)(ws + o_we);
  _Float16*      wtp  = (_Float16*)(ws + o_wp);
  _Float16*      wta  = (_Float16*)(ws + o_wa);

  (void)hipMemsetAsync(d_ws, 0, zero_bytes, stream);

  k_cvtw<<<(112 * 64 + 255) / 256, 256, 0, stream>>>(W_emb, wte, 64, 64, 0);
  k_cvtw<<<(112 * 128 + 255) / 256, 256, 0, stream>>>(pool_W, wtp, 108, 128, 0);
  k_cvtw<<<(112 * 128 + 255) / 256, 256, 0, stream>>>(pool_W + 11664, wtp + 112 * 128, 108, 128, 0);
  k_cvtw<<<(112 * 224 + 255) / 256, 256, 0, stream>>>(app_W, wta, 216, 224, 1);
  k_cvtw<<<(112 * 224 + 255) / 256, 256, 0, stream>>>(app_W + 23328, wta + 112 * 224, 216, 224, 1);

  k_scatter<<<(E + 4095) / 4096, 256, 0, stream>>>(src, dst, gcur, ebuf, E, nb);

  const int nbMM = (N + 127) / 128;
  k_mmf<2, 0><<<nbMM, 256, 0, stream>>>(nodes_feat, nullptr, wte, b_emb, h16, N);

  for (int i = 0; i < 2; i++) {
    k_mmf<4, 1><<<nbMM, 256, 0, stream>>>(h16, nullptr, wtp + i * 112 * 128,
                                          pool_b + i * HDIM, z8, N);
    k_bagg<<<nb, 256, 0, stream>>>(z8, ebuf, gcur, c16, N, nb);
    k_mmf<7, 2><<<nbMM, 256, 0, stream>>>(h16, c16, wta + i * 112 * 224,
                                          app_b + i * HDIM, h16, N);
  }

  k_cnt_bs<<<1, 128, 0, stream>>>(gid, cnt, N);
  k_readout<<<(N + 8 * 64 - 1) / (8 * 64), 256, 0, stream>>>(h16, gid, hg, N);
  k_div<<<(G_GRAPHS * HDIM + 255) / 256, 256, 0, stream>>>(hg, cnt, out, G_GRAPHS * HDIM);
}

// Round 9
// 368.725 us; speedup vs baseline: 4.3492x; 1.1556x over previous
//
#include <hip/hip_runtime.h>

#define HDIM 108
constexpr int G_GRAPHS = 128;
constexpr int MAXNB = 1024;   // max buckets (N up to 131072)
constexpr int CAP = 2560;     // slots per bucket (mean 2048, sigma ~45 -> +11 sigma)

typedef _Float16 half8 __attribute__((ext_vector_type(8)));
typedef _Float16 half4v __attribute__((ext_vector_type(4)));
typedef float floatx4 __attribute__((ext_vector_type(4)));
typedef float floatx2 __attribute__((ext_vector_type(2)));

// ---------------- fp8 e4m3 helpers (OCP on gfx950) ----------------
__device__ inline unsigned char f32_to_fp8(float t) {
#if __has_builtin(__builtin_amdgcn_cvt_pk_fp8_f32)
  return (unsigned char)(__builtin_amdgcn_cvt_pk_fp8_f32(t, t, 0, false) & 0xFF);
#else
  t = fminf(t, 448.f);
  if (t < 0.015625f) return (unsigned char)__float2int_rn(t * 512.f);
  unsigned u = __float_as_uint(t);
  unsigned lsb = (u >> 20) & 1;
  u += 0x7FFFFu + lsb;
  int e = (int)((u >> 23) & 0xFF) - 127;
  if (e > 8) return 0x7E;
  return (unsigned char)(((e + 7) << 3) | ((u >> 20) & 7));
#endif
}

template <bool HI>
__device__ inline floatx2 fp8x2_to_f32(unsigned v) {
#if __has_builtin(__builtin_amdgcn_cvt_pk_f32_fp8)
  return __builtin_amdgcn_cvt_pk_f32_fp8((int)v, HI);
#else
  unsigned b0 = HI ? ((v >> 16) & 0xFF) : (v & 0xFF);
  unsigned b1 = HI ? ((v >> 24) & 0xFF) : ((v >> 8) & 0xFF);
  floatx2 r;
  {
    unsigned s = b0 >> 7, e = (b0 >> 3) & 0xF, m = b0 & 7;
    float f = (e == 0) ? (float)m * 0.001953125f
                       : __uint_as_float(((e + 120u) << 23) | (m << 20));
    r[0] = s ? -f : f;
  }
  {
    unsigned s = b1 >> 7, e = (b1 >> 3) & 0xF, m = b1 & 7;
    float f = (e == 0) ? (float)m * 0.001953125f
                       : __uint_as_float(((e + 120u) << 23) | (m << 20));
    r[1] = s ? -f : f;
  }
  return r;
#endif
}

// ---------------- weight convert: fp32 [K][108] -> fp16 transposed padded [112][Kpad] ----
__global__ __launch_bounds__(256) void k_cvtw(const float* __restrict__ src, _Float16* __restrict__ dst,
                                              int K, int Kpad, int split) {
  int idx = blockIdx.x * 256 + threadIdx.x;
  int total = 112 * Kpad;
  if (idx >= total) return;
  int n = idx / Kpad, k = idx - n * Kpad;
  int ks;
  if (split) ks = (k < 108) ? k : (k >= 112 && k < 220) ? (k - 4) : -1;
  else       ks = (k < K) ? k : -1;
  float v = (n < 108 && ks >= 0) ? src[ks * 108 + n] : 0.f;
  dst[idx] = (_Float16)v;
}

// ---------------- bucket partition: edges -> packed (src | ld<<20) grouped by dst>>7 --------
__global__ __launch_bounds__(256) void k_scatter(const int* __restrict__ src, const int* __restrict__ dst,
                                                 int* __restrict__ gcur, int* __restrict__ ebuf,
                                                 int E, int nb) {
  __shared__ int hist[MAXNB];
  const int tid = threadIdx.x;
  const int e0 = blockIdx.x * 4096;
  for (int b = tid; b < nb; b += 256) hist[b] = 0;
  __syncthreads();
#pragma unroll
  for (int it = 0; it < 16; it++) {
    int e = e0 + it * 256 + tid;
    if (e < E) atomicAdd(&hist[dst[e] >> 7], 1);
  }
  __syncthreads();
  for (int b = tid; b < nb; b += 256) {
    int h = hist[b];
    hist[b] = h ? atomicAdd(&gcur[b * 16], h) : 0;
  }
  __syncthreads();
#pragma unroll
  for (int it = 0; it < 16; it++) {
    int e = e0 + it * 256 + tid;
    if (e < E) {
      int d = dst[e];
      int b = d >> 7;
      int rank = atomicAdd(&hist[b], 1);
      if (rank < CAP) ebuf[(size_t)b * CAP + rank] = src[e] | ((d & 127) << 20);
    }
  }
}

// ---------------- bucket aggregation: c16[v] = mean_{e: dst==v} fp8 z[src[e]] ---------------
// 1024-thread blocks (16 waves) for latency hiding: 32 groups of 32 lanes, each group
// gathers 4 of the bucket's 128 rows; loop unrolled x4 for outstanding-load MLP.
__global__ __launch_bounds__(1024) void k_bagg(const unsigned char* __restrict__ z, const int* __restrict__ ebuf,
                                               const int* __restrict__ gcur, _Float16* __restrict__ c16,
                                               int N, int nb) {
  __shared__ int cnts[128];
  __shared__ int scanb[128];
  __shared__ int off[129];
  __shared__ int ecur[128];
  __shared__ int esrc[CAP];
  const int tid = threadIdx.x;
  const int b = blockIdx.x;
  const int v0 = b << 7;
  int cntb = gcur[b * 16];
  if (cntb > CAP) cntb = CAP;
  const int* eb = ebuf + (size_t)b * CAP;

  if (tid < 128) cnts[tid] = 0;
  __syncthreads();
  for (int i = tid; i < cntb; i += 1024) atomicAdd(&cnts[eb[i] >> 20], 1);
  __syncthreads();
  if (tid < 128) scanb[tid] = cnts[tid];
  __syncthreads();
#pragma unroll
  for (int st = 1; st < 128; st <<= 1) {
    int v = 0;
    if (tid < 128 && tid >= st) v = scanb[tid - st];
    __syncthreads();
    if (tid < 128) scanb[tid] += v;
    __syncthreads();
  }
  if (tid == 0) off[0] = 0;
  if (tid < 128) {
    off[tid + 1] = scanb[tid];
    ecur[tid] = scanb[tid] - cnts[tid];
  }
  __syncthreads();
  for (int i = tid; i < cntb; i += 1024) {
    int e = eb[i];
    int p = atomicAdd(&ecur[e >> 20], 1);
    esrc[p] = e & 0xFFFFF;
  }
  __syncthreads();

  const int lane = tid & 31;
  const int grp = tid >> 5;                 // 32 groups of 32 (28 active lanes)
  if (lane >= 28) return;
  const unsigned char* __restrict__ zl = z + lane * 4;
#pragma unroll 1
  for (int r = grp; r < 128; r += 32) {
    int v = v0 + r;
    if (v >= N) continue;
    int s = off[r], e2 = off[r + 1];
    float a0 = 0.f, a1 = 0.f, a2 = 0.f, a3 = 0.f;
    int j = s;
    for (; j + 4 <= e2; j += 4) {
      unsigned q0 = *(const unsigned*)(zl + (size_t)esrc[j] * 112);
      unsigned q1 = *(const unsigned*)(zl + (size_t)esrc[j + 1] * 112);
      unsigned q2 = *(const unsigned*)(zl + (size_t)esrc[j + 2] * 112);
      unsigned q3 = *(const unsigned*)(zl + (size_t)esrc[j + 3] * 112);
      floatx2 l0 = fp8x2_to_f32<false>(q0), h0 = fp8x2_to_f32<true>(q0);
      floatx2 l1 = fp8x2_to_f32<false>(q1), h1 = fp8x2_to_f32<true>(q1);
      floatx2 l2 = fp8x2_to_f32<false>(q2), h2 = fp8x2_to_f32<true>(q2);
      floatx2 l3 = fp8x2_to_f32<false>(q3), h3 = fp8x2_to_f32<true>(q3);
      a0 += (l0[0] + l1[0]) + (l2[0] + l3[0]);
      a1 += (l0[1] + l1[1]) + (l2[1] + l3[1]);
      a2 += (h0[0] + h1[0]) + (h2[0] + h3[0]);
      a3 += (h0[1] + h1[1]) + (h2[1] + h3[1]);
    }
    for (; j < e2; j++) {
      unsigned q0 = *(const unsigned*)(zl + (size_t)esrc[j] * 112);
      floatx2 l0 = fp8x2_to_f32<false>(q0), h0 = fp8x2_to_f32<true>(q0);
      a0 += l0[0]; a1 += l0[1]; a2 += h0[0]; a3 += h0[1];
    }
    int d = e2 - s;
    float inv = 1.f / (float)(d > 0 ? d : 1);
    half4v r4;
    r4[0] = (_Float16)(a0 * inv); r4[1] = (_Float16)(a1 * inv);
    r4[2] = (_Float16)(a2 * inv); r4[3] = (_Float16)(a3 * inv);
    *(half4v*)(c16 + (size_t)v * 112 + lane * 4) = r4;
  }
}

// ---------------- MFMA GEMM: out[N,108] = A[N,K'] @ W'[K',108] (+bias, act) ----------------
// MODE 0: emb (fp32 feat in, +bias -> h16). MODE 1: pool (+bias, ReLU -> fp8 z).
// MODE 2: app ([h16|gap|c16]; +bias -> row L2 norm -> ReLU -> residual into h16).
template <int KCH, int MODE>
__global__ __launch_bounds__(256, 2) void k_mmf(const void* Asrc, const _Float16* __restrict__ c16,
                                                const _Float16* __restrict__ Wt, const float* __restrict__ bias,
                                                void* outp, int N) {
  constexpr int KW = KCH * 32;
  __shared__ _Float16 As[128 * 40];
  __shared__ _Float16 Ws[112 * 40];

  const int tid = threadIdx.x;
  const int wave = tid >> 6;
  const int lane = tid & 63;
  const int lo = lane & 15;
  const int quad = lane >> 4;
  const int n0 = blockIdx.x * 128;
  const _Float16* h16 = (const _Float16*)Asrc;
  const float* feat = (const float*)Asrc;

  floatx4 acc[2][7];
#pragma unroll
  for (int rt = 0; rt < 2; rt++)
#pragma unroll
    for (int ct = 0; ct < 7; ct++) {
      floatx4 zz = {0.f, 0.f, 0.f, 0.f};
      acc[rt][ct] = zz;
    }

#pragma unroll 1
  for (int kc = 0; kc < KCH; kc++) {
#pragma unroll
    for (int it = 0; it < 2; it++) {
      int idx = tid + it * 256;
      int r = idx >> 2, sg = idx & 3;
      int gn = n0 + r;
      int k = kc * 32 + sg * 8;
      half8 v = {0, 0, 0, 0, 0, 0, 0, 0};
      if (gn < N) {
        if (MODE == 0) {
          float4 f0 = *(const float4*)(feat + (size_t)gn * 64 + k);
          float4 f1 = *(const float4*)(feat + (size_t)gn * 64 + k + 4);
          v[0] = (_Float16)f0.x; v[1] = (_Float16)f0.y; v[2] = (_Float16)f0.z; v[3] = (_Float16)f0.w;
          v[4] = (_Float16)f1.x; v[5] = (_Float16)f1.y; v[6] = (_Float16)f1.z; v[7] = (_Float16)f1.w;
        } else if (MODE == 2) {
          const _Float16* sp = (k < 112) ? (h16 + (size_t)gn * 112 + k)
                                         : (c16 + (size_t)gn * 112 + (k - 112));
          v = *(const half8*)sp;
        } else {  // MODE 1: K'=128, cols 112..127 are zero
          if (k < 112) v = *(const half8*)(h16 + (size_t)gn * 112 + k);
        }
      }
      *(half8*)&As[r * 40 + sg * 8] = v;
    }
#pragma unroll
    for (int it = 0; it < 2; it++) {
      int idx = tid + it * 256;
      if (idx < 112 * 4) {
        int nrow = idx >> 2, sg = idx & 3;
        half8 v = *(const half8*)(Wt + (size_t)nrow * KW + kc * 32 + sg * 8);
        *(half8*)&Ws[nrow * 40 + sg * 8] = v;
      }
    }
    __syncthreads();

    half8 a0 = *(const half8*)&As[(wave * 32 + lo) * 40 + quad * 8];
    half8 a1 = *(const half8*)&As[(wave * 32 + 16 + lo) * 40 + quad * 8];
#pragma unroll
    for (int ct = 0; ct < 7; ct++) {
      half8 b = *(const half8*)&Ws[(ct * 16 + lo) * 40 + quad * 8];
      acc[0][ct] = __builtin_amdgcn_mfma_f32_16x16x32_f16(a0, b, acc[0][ct], 0, 0, 0);
      acc[1][ct] = __builtin_amdgcn_mfma_f32_16x16x32_f16(a1, b, acc[1][ct], 0, 0, 0);
    }
    __syncthreads();
  }

  float bias_v[7];
#pragma unroll
  for (int ct = 0; ct < 7; ct++) {
    int col = ct * 16 + lo;
    bias_v[ct] = (col < 108) ? bias[col] : 0.f;
  }

  if (MODE == 2) {
    _Float16* out16 = (_Float16*)outp;
#pragma unroll
    for (int rt = 0; rt < 2; rt++) {
#pragma unroll
      for (int reg = 0; reg < 4; reg++) {
        int gr = n0 + wave * 32 + rt * 16 + quad * 4 + reg;
        float bv[7];
        float ssq = 0.f;
#pragma unroll
        for (int ct = 0; ct < 7; ct++) {
          float t = acc[rt][ct][reg] + bias_v[ct];  // == 0 at pad cols
          bv[ct] = t;
          ssq += t * t;
        }
#pragma unroll
        for (int s = 1; s < 16; s <<= 1) ssq += __shfl_xor(ssq, s, 16);
        float scale = 1.f / fmaxf(sqrtf(ssq), 1e-12f);
        if (gr < N) {
          _Float16* hp = out16 + (size_t)gr * 112 + lo;
#pragma unroll
          for (int ct = 0; ct < 7; ct++) {
            float hv = (float)hp[ct * 16];
            hp[ct * 16] = (_Float16)(hv + fmaxf(bv[ct] * scale, 0.f));
          }
        }
      }
    }
  } else if (MODE == 1) {
    unsigned char* outb = (unsigned char*)outp;
#pragma unroll
    for (int rt = 0; rt < 2; rt++) {
#pragma unroll
      for (int reg = 0; reg < 4; reg++) {
        int gr = n0 + wave * 32 + rt * 16 + quad * 4 + reg;
        if (gr < N) {
          unsigned char* op = outb + (size_t)gr * 112 + lo;
#pragma unroll
          for (int ct = 0; ct < 7; ct++) {
            float t = fmaxf(acc[rt][ct][reg] + bias_v[ct], 0.f);  // pad cols -> 0
            op[ct * 16] = f32_to_fp8(t);
          }
        }
      }
    }
  } else {
    _Float16* out16 = (_Float16*)outp;
#pragma unroll
    for (int rt = 0; rt < 2; rt++) {
#pragma unroll
      for (int reg = 0; reg < 4; reg++) {
        int gr = n0 + wave * 32 + rt * 16 + quad * 4 + reg;
        if (gr < N) {
          _Float16* op = out16 + (size_t)gr * 112 + lo;
#pragma unroll
          for (int ct = 0; ct < 7; ct++) {
            float t = acc[rt][ct][reg] + bias_v[ct];
            op[ct * 16] = (_Float16)t;  // pad cols get 0
          }
        }
      }
    }
  }
}

// ---------------- readout ----------------
__global__ __launch_bounds__(128) void k_cnt_bs(const int* __restrict__ gid, int* __restrict__ cnt, int N) {
  int g = threadIdx.x;
  if (g >= G_GRAPHS) return;
  int lo = 0, hi = N;
  while (lo < hi) { int m = (lo + hi) >> 1; if (gid[m] < g) lo = m + 1; else hi = m; }
  int lb = lo;
  lo = 0; hi = N;
  while (lo < hi) { int m = (lo + hi) >> 1; if (gid[m] <= g) lo = m + 1; else hi = m; }
  cnt[g] = lo - lb;
}

__global__ __launch_bounds__(256) void k_readout(const _Float16* __restrict__ h, const int* __restrict__ gid,
                                                 float* __restrict__ hg, int N) {
  const int CH = 64;
  const int lane = threadIdx.x & 31;
  const int grp = threadIdx.x >> 5;
  int start = (blockIdx.x * 8 + grp) * CH;
  if (start >= N || lane >= 27) return;
  int end = min(start + CH, N);
  float a0 = 0.f, a1 = 0.f, a2 = 0.f, a3 = 0.f;
  int cur = gid[start];  // sorted graph_ids -> run-length pre-aggregation
  for (int i = start; i < end; i++) {
    int g = gid[i];
    if (g != cur) {
      float* base = &hg[(size_t)cur * HDIM + lane * 4];
      atomicAdd(base + 0, a0); atomicAdd(base + 1, a1);
      atomicAdd(base + 2, a2); atomicAdd(base + 3, a3);
      a0 = a1 = a2 = a3 = 0.f;
      cur = g;
    }
    half4v v = *(const half4v*)(h + (size_t)i * 112 + lane * 4);
    a0 += (float)v[0]; a1 += (float)v[1]; a2 += (float)v[2]; a3 += (float)v[3];
  }
  float* base = &hg[(size_t)cur * HDIM + lane * 4];
  atomicAdd(base + 0, a0); atomicAdd(base + 1, a1);
  atomicAdd(base + 2, a2); atomicAdd(base + 3, a3);
}

__global__ __launch_bounds__(256) void k_div(const float* __restrict__ hg, const int* __restrict__ cnt,
                                             float* __restrict__ out, int total) {
  int i = blockIdx.x * 256 + threadIdx.x;
  if (i < total) {
    int g = i / HDIM;
    int c = cnt[g];
    out[i] = hg[i] / (float)(c > 0 ? c : 1);
  }
}

// ---------------- launch ----------------
extern "C" void kernel_launch(void* const* d_in, const int* in_sizes, int n_in,
                              void* d_out, int out_size, void* d_ws, size_t ws_size,
                              hipStream_t stream) {
  (void)n_in; (void)ws_size; (void)out_size;
  const float* nodes_feat = (const float*)d_in[0];
  const float* W_emb = (const float*)d_in[4];
  const float* b_emb = (const float*)d_in[5];
  const float* pool_W = (const float*)d_in[6];
  const float* pool_b = (const float*)d_in[7];
  const float* app_W = (const float*)d_in[8];
  const float* app_b = (const float*)d_in[9];
  const int* src = (const int*)d_in[10];
  const int* dst = (const int*)d_in[11];
  const int* gid = (const int*)d_in[12];
  const int N = in_sizes[2];
  const int E = in_sizes[10];
  float* out = (float*)d_out;

  const int nb = (N + 127) >> 7;

  char* ws = (char*)d_ws;
  size_t off = 0;
  auto alloc = [&](size_t bytes) -> size_t {
    size_t o = off;
    off += (bytes + 1023) & ~size_t(1023);
    return o;
  };
  size_t o_gcur = alloc((size_t)MAXNB * 16 * 4);
  size_t o_cnt  = alloc((size_t)G_GRAPHS * 4);
  size_t o_hg   = alloc((size_t)G_GRAPHS * HDIM * 4);
  size_t zero_bytes = off;  // [gcur, cnt, hg]
  size_t o_ebuf = alloc((size_t)MAXNB * CAP * 4);     // packed src|ld<<20
  size_t o_h  = alloc((size_t)N * 112 * 2);
  size_t o_z  = alloc((size_t)N * 112);               // fp8 z
  size_t o_c  = alloc((size_t)N * 112 * 2);
  size_t o_we = alloc((size_t)112 * 64 * 2);
  size_t o_wp = alloc((size_t)2 * 112 * 128 * 2);
  size_t o_wa = alloc((size_t)2 * 112 * 224 * 2);

  int*           gcur = (int*)(ws + o_gcur);
  int*           cnt  = (int*)(ws + o_cnt);
  float*         hg   = (float*)(ws + o_hg);
  int*           ebuf = (int*)(ws + o_ebuf);
  _Float16*      h16  = (_Float16*)(ws + o_h);
  unsigned char* z8   = (unsigned char*)(ws + o_z);
  _Float16*      c16  = (_Float16*)(ws + o_c);
  _Float16*      wte  = (_Float16*)(ws + o_we);
  _Float16*      wtp  = (_Float16*)(ws + o_wp);
  _Float16*      wta  = (_Float16*)(ws + o_wa);

  (void)hipMemsetAsync(d_ws, 0, zero_bytes, stream);

  k_cvtw<<<(112 * 64 + 255) / 256, 256, 0, stream>>>(W_emb, wte, 64, 64, 0);
  k_cvtw<<<(112 * 128 + 255) / 256, 256, 0, stream>>>(pool_W, wtp, 108, 128, 0);
  k_cvtw<<<(112 * 128 + 255) / 256, 256, 0, stream>>>(pool_W + 11664, wtp + 112 * 128, 108, 128, 0);
  k_cvtw<<<(112 * 224 + 255) / 256, 256, 0, stream>>>(app_W, wta, 216, 224, 1);
  k_cvtw<<<(112 * 224 + 255) / 256, 256, 0, stream>>>(app_W + 23328, wta + 112 * 224, 216, 224, 1);

  k_scatter<<<(E + 4095) / 4096, 256, 0, stream>>>(src, dst, gcur, ebuf, E, nb);

  const int nbMM = (N + 127) / 128;
  k_mmf<2, 0><<<nbMM, 256, 0, stream>>>(nodes_feat, nullptr, wte, b_emb, h16, N);

  for (int i = 0; i < 2; i++) {
    k_mmf<4, 1><<<nbMM, 256, 0, stream>>>(h16, nullptr, wtp + i * 112 * 128,
                                          pool_b + i * HDIM, z8, N);
    k_bagg<<<nb, 1024, 0, stream>>>(z8, ebuf, gcur, c16, N, nb);
    k_mmf<7, 2><<<nbMM, 256, 0, stream>>>(h16, c16, wta + i * 112 * 224,
                                          app_b + i * HDIM, h16, N);
  }

  k_cnt_bs<<<1, 128, 0, stream>>>(gid, cnt, N);
  k_readout<<<(N + 8 * 64 - 1) / (8 * 64), 256, 0, stream>>>(h16, gid, hg, N);
  k_div<<<(G_GRAPHS * HDIM + 255) / 256, 256, 0, stream>>>(hg, cnt, out, G_GRAPHS * HDIM);
}

// Round 10
// 348.578 us; speedup vs baseline: 4.6006x; 1.0578x over previous
//
#include <hip/hip_runtime.h>

#define HDIM 108
constexpr int G_GRAPHS = 128;
constexpr int MAXNB = 1024;   // max buckets (N up to 131072)
constexpr int CAP = 2560;     // slots per bucket (mean 2048, sigma ~45 -> +11 sigma)

typedef _Float16 half8 __attribute__((ext_vector_type(8)));
typedef _Float16 half4v __attribute__((ext_vector_type(4)));
typedef float floatx4 __attribute__((ext_vector_type(4)));
typedef float floatx2 __attribute__((ext_vector_type(2)));

// ---------------- fp8 e4m3 helpers (OCP on gfx950) ----------------
__device__ inline unsigned char f32_to_fp8(float t) {
#if __has_builtin(__builtin_amdgcn_cvt_pk_fp8_f32)
  return (unsigned char)(__builtin_amdgcn_cvt_pk_fp8_f32(t, t, 0, false) & 0xFF);
#else
  t = fminf(t, 448.f);
  if (t < 0.015625f) return (unsigned char)__float2int_rn(t * 512.f);
  unsigned u = __float_as_uint(t);
  unsigned lsb = (u >> 20) & 1;
  u += 0x7FFFFu + lsb;
  int e = (int)((u >> 23) & 0xFF) - 127;
  if (e > 8) return 0x7E;
  return (unsigned char)(((e + 7) << 3) | ((u >> 20) & 7));
#endif
}

template <bool HI>
__device__ inline floatx2 fp8x2_to_f32(unsigned v) {
#if __has_builtin(__builtin_amdgcn_cvt_pk_f32_fp8)
  return __builtin_amdgcn_cvt_pk_f32_fp8((int)v, HI);
#else
  unsigned b0 = HI ? ((v >> 16) & 0xFF) : (v & 0xFF);
  unsigned b1 = HI ? ((v >> 24) & 0xFF) : ((v >> 8) & 0xFF);
  floatx2 r;
  {
    unsigned s = b0 >> 7, e = (b0 >> 3) & 0xF, m = b0 & 7;
    float f = (e == 0) ? (float)m * 0.001953125f
                       : __uint_as_float(((e + 120u) << 23) | (m << 20));
    r[0] = s ? -f : f;
  }
  {
    unsigned s = b1 >> 7, e = (b1 >> 3) & 0xF, m = b1 & 7;
    float f = (e == 0) ? (float)m * 0.001953125f
                       : __uint_as_float(((e + 120u) << 23) | (m << 20));
    r[1] = s ? -f : f;
  }
  return r;
#endif
}

// ---------------- fused weight convert: all layers in one dispatch ----------------
// Segments (flat idx): [0,7168) emb Kpad=64; [7168,21504) pool0; [21504,35840) pool1 (Kpad=128);
// [35840,60928) app0; [60928,86016) app1 (Kpad=224, split remap).
__global__ __launch_bounds__(256) void k_cvtall(const float* __restrict__ W_emb,
                                                const float* __restrict__ pool_W,
                                                const float* __restrict__ app_W,
                                                _Float16* __restrict__ wte,
                                                _Float16* __restrict__ wtp,
                                                _Float16* __restrict__ wta) {
  int idx = blockIdx.x * 256 + threadIdx.x;
  if (idx >= 86016) return;
  const float* src;
  _Float16* dst;
  int Kpad, K, split, rel;
  if (idx < 7168)       { rel = idx;          src = W_emb;            dst = wte;              Kpad = 64;  K = 64;  split = 0; }
  else if (idx < 21504) { rel = idx - 7168;   src = pool_W;           dst = wtp;              Kpad = 128; K = 108; split = 0; }
  else if (idx < 35840) { rel = idx - 21504;  src = pool_W + 11664;   dst = wtp + 14336;      Kpad = 128; K = 108; split = 0; }
  else if (idx < 60928) { rel = idx - 35840;  src = app_W;            dst = wta;              Kpad = 224; K = 216; split = 1; }
  else                  { rel = idx - 60928;  src = app_W + 23328;    dst = wta + 25088;      Kpad = 224; K = 216; split = 1; }
  int n = rel / Kpad, k = rel - n * Kpad;
  int ks;
  if (split) ks = (k < 108) ? k : (k >= 112 && k < 220) ? (k - 4) : -1;
  else       ks = (k < K) ? k : -1;
  float v = (n < 108 && ks >= 0) ? src[ks * 108 + n] : 0.f;
  dst[rel] = (_Float16)v;
}

// ---------------- bucket partition: edges -> packed (src | ld<<20) grouped by dst>>7 --------
// 1024-thread blocks, 16384 edges each (~98 blocks): 4x fewer blocks -> 4x shorter
// per-counter atomic chains, and ~21 consecutive ebuf entries per (block,bucket)
// -> ~2 cache lines per reservation instead of per-entry line ping-pong.
__global__ __launch_bounds__(1024) void k_scatter(const int* __restrict__ src, const int* __restrict__ dst,
                                                  int* __restrict__ gcur, int* __restrict__ ebuf,
                                                  int E, int nb) {
  __shared__ int hist[MAXNB];
  const int tid = threadIdx.x;
  const int e0 = blockIdx.x * 16384;
  for (int b = tid; b < nb; b += 1024) hist[b] = 0;
  __syncthreads();
#pragma unroll
  for (int it = 0; it < 16; it++) {
    int e = e0 + it * 1024 + tid;
    if (e < E) atomicAdd(&hist[dst[e] >> 7], 1);
  }
  __syncthreads();
  for (int b = tid; b < nb; b += 1024) {
    int h = hist[b];
    hist[b] = h ? atomicAdd(&gcur[b * 16], h) : 0;
  }
  __syncthreads();
#pragma unroll
  for (int it = 0; it < 16; it++) {
    int e = e0 + it * 1024 + tid;
    if (e < E) {
      int d = dst[e];
      int b = d >> 7;
      int rank = atomicAdd(&hist[b], 1);
      if (rank < CAP) ebuf[(size_t)b * CAP + rank] = src[e] | ((d & 127) << 20);
    }
  }
}

// ---------------- bucket aggregation: c16[v] = mean_{e: dst==v} fp8 z[src[e]] ---------------
// 1024-thread blocks (16 waves): 32 groups of 32 lanes, 4 rows/group, x4 unroll for MLP.
__global__ __launch_bounds__(1024) void k_bagg(const unsigned char* __restrict__ z, const int* __restrict__ ebuf,
                                               const int* __restrict__ gcur, _Float16* __restrict__ c16,
                                               int N, int nb) {
  __shared__ int cnts[128];
  __shared__ int scanb[128];
  __shared__ int off[129];
  __shared__ int ecur[128];
  __shared__ int esrc[CAP];
  const int tid = threadIdx.x;
  const int b = blockIdx.x;
  const int v0 = b << 7;
  int cntb = gcur[b * 16];
  if (cntb > CAP) cntb = CAP;
  const int* eb = ebuf + (size_t)b * CAP;

  if (tid < 128) cnts[tid] = 0;
  __syncthreads();
  for (int i = tid; i < cntb; i += 1024) atomicAdd(&cnts[eb[i] >> 20], 1);
  __syncthreads();
  if (tid < 128) scanb[tid] = cnts[tid];
  __syncthreads();
#pragma unroll
  for (int st = 1; st < 128; st <<= 1) {
    int v = 0;
    if (tid < 128 && tid >= st) v = scanb[tid - st];
    __syncthreads();
    if (tid < 128) scanb[tid] += v;
    __syncthreads();
  }
  if (tid == 0) off[0] = 0;
  if (tid < 128) {
    off[tid + 1] = scanb[tid];
    ecur[tid] = scanb[tid] - cnts[tid];
  }
  __syncthreads();
  for (int i = tid; i < cntb; i += 1024) {
    int e = eb[i];
    int p = atomicAdd(&ecur[e >> 20], 1);
    esrc[p] = e & 0xFFFFF;
  }
  __syncthreads();

  const int lane = tid & 31;
  const int grp = tid >> 5;                 // 32 groups of 32 (28 active lanes)
  if (lane >= 28) return;
  const unsigned char* __restrict__ zl = z + lane * 4;
#pragma unroll 1
  for (int r = grp; r < 128; r += 32) {
    int v = v0 + r;
    if (v >= N) continue;
    int s = off[r], e2 = off[r + 1];
    float a0 = 0.f, a1 = 0.f, a2 = 0.f, a3 = 0.f;
    int j = s;
    for (; j + 4 <= e2; j += 4) {
      unsigned q0 = *(const unsigned*)(zl + (size_t)esrc[j] * 112);
      unsigned q1 = *(const unsigned*)(zl + (size_t)esrc[j + 1] * 112);
      unsigned q2 = *(const unsigned*)(zl + (size_t)esrc[j + 2] * 112);
      unsigned q3 = *(const unsigned*)(zl + (size_t)esrc[j + 3] * 112);
      floatx2 l0 = fp8x2_to_f32<false>(q0), h0 = fp8x2_to_f32<true>(q0);
      floatx2 l1 = fp8x2_to_f32<false>(q1), h1 = fp8x2_to_f32<true>(q1);
      floatx2 l2 = fp8x2_to_f32<false>(q2), h2 = fp8x2_to_f32<true>(q2);
      floatx2 l3 = fp8x2_to_f32<false>(q3), h3 = fp8x2_to_f32<true>(q3);
      a0 += (l0[0] + l1[0]) + (l2[0] + l3[0]);
      a1 += (l0[1] + l1[1]) + (l2[1] + l3[1]);
      a2 += (h0[0] + h1[0]) + (h2[0] + h3[0]);
      a3 += (h0[1] + h1[1]) + (h2[1] + h3[1]);
    }
    for (; j < e2; j++) {
      unsigned q0 = *(const unsigned*)(zl + (size_t)esrc[j] * 112);
      floatx2 l0 = fp8x2_to_f32<false>(q0), h0 = fp8x2_to_f32<true>(q0);
      a0 += l0[0]; a1 += l0[1]; a2 += h0[0]; a3 += h0[1];
    }
    int d = e2 - s;
    float inv = 1.f / (float)(d > 0 ? d : 1);
    half4v r4;
    r4[0] = (_Float16)(a0 * inv); r4[1] = (_Float16)(a1 * inv);
    r4[2] = (_Float16)(a2 * inv); r4[3] = (_Float16)(a3 * inv);
    *(half4v*)(c16 + (size_t)v * 112 + lane * 4) = r4;
  }
}

// ---------------- MFMA GEMM: out[N,108] = A[N,K'] @ W'[K',108] (+bias, act) ----------------
// MODE 0: emb (fp32 feat in, +bias -> h16). MODE 1: pool (+bias, ReLU -> fp8 z).
// MODE 2: app ([h16|gap|c16]; +bias -> row L2 norm -> ReLU -> residual into h16).
template <int KCH, int MODE>
__global__ __launch_bounds__(256, 2) void k_mmf(const void* Asrc, const _Float16* __restrict__ c16,
                                                const _Float16* __restrict__ Wt, const float* __restrict__ bias,
                                                void* outp, int N) {
  constexpr int KW = KCH * 32;
  __shared__ _Float16 As[128 * 40];
  __shared__ _Float16 Ws[112 * 40];

  const int tid = threadIdx.x;
  const int wave = tid >> 6;
  const int lane = tid & 63;
  const int lo = lane & 15;
  const int quad = lane >> 4;
  const int n0 = blockIdx.x * 128;
  const _Float16* h16 = (const _Float16*)Asrc;
  const float* feat = (const float*)Asrc;

  floatx4 acc[2][7];
#pragma unroll
  for (int rt = 0; rt < 2; rt++)
#pragma unroll
    for (int ct = 0; ct < 7; ct++) {
      floatx4 zz = {0.f, 0.f, 0.f, 0.f};
      acc[rt][ct] = zz;
    }

#pragma unroll 1
  for (int kc = 0; kc < KCH; kc++) {
#pragma unroll
    for (int it = 0; it < 2; it++) {
      int idx = tid + it * 256;
      int r = idx >> 2, sg = idx & 3;
      int gn = n0 + r;
      int k = kc * 32 + sg * 8;
      half8 v = {0, 0, 0, 0, 0, 0, 0, 0};
      if (gn < N) {
        if (MODE == 0) {
          float4 f0 = *(const float4*)(feat + (size_t)gn * 64 + k);
          float4 f1 = *(const float4*)(feat + (size_t)gn * 64 + k + 4);
          v[0] = (_Float16)f0.x; v[1] = (_Float16)f0.y; v[2] = (_Float16)f0.z; v[3] = (_Float16)f0.w;
          v[4] = (_Float16)f1.x; v[5] = (_Float16)f1.y; v[6] = (_Float16)f1.z; v[7] = (_Float16)f1.w;
        } else if (MODE == 2) {
          const _Float16* sp = (k < 112) ? (h16 + (size_t)gn * 112 + k)
                                         : (c16 + (size_t)gn * 112 + (k - 112));
          v = *(const half8*)sp;
        } else {  // MODE 1: K'=128, cols 112..127 are zero
          if (k < 112) v = *(const half8*)(h16 + (size_t)gn * 112 + k);
        }
      }
      *(half8*)&As[r * 40 + sg * 8] = v;
    }
#pragma unroll
    for (int it = 0; it < 2; it++) {
      int idx = tid + it * 256;
      if (idx < 112 * 4) {
        int nrow = idx >> 2, sg = idx & 3;
        half8 v = *(const half8*)(Wt + (size_t)nrow * KW + kc * 32 + sg * 8);
        *(half8*)&Ws[nrow * 40 + sg * 8] = v;
      }
    }
    __syncthreads();

    half8 a0 = *(const half8*)&As[(wave * 32 + lo) * 40 + quad * 8];
    half8 a1 = *(const half8*)&As[(wave * 32 + 16 + lo) * 40 + quad * 8];
#pragma unroll
    for (int ct = 0; ct < 7; ct++) {
      half8 b = *(const half8*)&Ws[(ct * 16 + lo) * 40 + quad * 8];
      acc[0][ct] = __builtin_amdgcn_mfma_f32_16x16x32_f16(a0, b, acc[0][ct], 0, 0, 0);
      acc[1][ct] = __builtin_amdgcn_mfma_f32_16x16x32_f16(a1, b, acc[1][ct], 0, 0, 0);
    }
    __syncthreads();
  }

  float bias_v[7];
#pragma unroll
  for (int ct = 0; ct < 7; ct++) {
    int col = ct * 16 + lo;
    bias_v[ct] = (col < 108) ? bias[col] : 0.f;
  }

  if (MODE == 2) {
    _Float16* out16 = (_Float16*)outp;
#pragma unroll
    for (int rt = 0; rt < 2; rt++) {
#pragma unroll
      for (int reg = 0; reg < 4; reg++) {
        int gr = n0 + wave * 32 + rt * 16 + quad * 4 + reg;
        float bv[7];
        float ssq = 0.f;
#pragma unroll
        for (int ct = 0; ct < 7; ct++) {
          float t = acc[rt][ct][reg] + bias_v[ct];  // == 0 at pad cols
          bv[ct] = t;
          ssq += t * t;
        }
#pragma unroll
        for (int s = 1; s < 16; s <<= 1) ssq += __shfl_xor(ssq, s, 16);
        float scale = 1.f / fmaxf(sqrtf(ssq), 1e-12f);
        if (gr < N) {
          _Float16* hp = out16 + (size_t)gr * 112 + lo;
#pragma unroll
          for (int ct = 0; ct < 7; ct++) {
            float hv = (float)hp[ct * 16];
            hp[ct * 16] = (_Float16)(hv + fmaxf(bv[ct] * scale, 0.f));
          }
        }
      }
    }
  } else if (MODE == 1) {
    unsigned char* outb = (unsigned char*)outp;
#pragma unroll
    for (int rt = 0; rt < 2; rt++) {
#pragma unroll
      for (int reg = 0; reg < 4; reg++) {
        int gr = n0 + wave * 32 + rt * 16 + quad * 4 + reg;
        if (gr < N) {
          unsigned char* op = outb + (size_t)gr * 112 + lo;
#pragma unroll
          for (int ct = 0; ct < 7; ct++) {
            float t = fmaxf(acc[rt][ct][reg] + bias_v[ct], 0.f);  // pad cols -> 0
            op[ct * 16] = f32_to_fp8(t);
          }
        }
      }
    }
  } else {
    _Float16* out16 = (_Float16*)outp;
#pragma unroll
    for (int rt = 0; rt < 2; rt++) {
#pragma unroll
      for (int reg = 0; reg < 4; reg++) {
        int gr = n0 + wave * 32 + rt * 16 + quad * 4 + reg;
        if (gr < N) {
          _Float16* op = out16 + (size_t)gr * 112 + lo;
#pragma unroll
          for (int ct = 0; ct < 7; ct++) {
            float t = acc[rt][ct][reg] + bias_v[ct];
            op[ct * 16] = (_Float16)t;  // pad cols get 0
          }
        }
      }
    }
  }
}

// ---------------- readout ----------------
__global__ __launch_bounds__(256) void k_readout(const _Float16* __restrict__ h, const int* __restrict__ gid,
                                                 float* __restrict__ hg, int N) {
  const int CH = 64;
  const int lane = threadIdx.x & 31;
  const int grp = threadIdx.x >> 5;
  int start = (blockIdx.x * 8 + grp) * CH;
  if (start >= N || lane >= 27) return;
  int end = min(start + CH, N);
  float a0 = 0.f, a1 = 0.f, a2 = 0.f, a3 = 0.f;
  int cur = gid[start];  // sorted graph_ids -> run-length pre-aggregation
  for (int i = start; i < end; i++) {
    int g = gid[i];
    if (g != cur) {
      float* base = &hg[(size_t)cur * HDIM + lane * 4];
      atomicAdd(base + 0, a0); atomicAdd(base + 1, a1);
      atomicAdd(base + 2, a2); atomicAdd(base + 3, a3);
      a0 = a1 = a2 = a3 = 0.f;
      cur = g;
    }
    half4v v = *(const half4v*)(h + (size_t)i * 112 + lane * 4);
    a0 += (float)v[0]; a1 += (float)v[1]; a2 += (float)v[2]; a3 += (float)v[3];
  }
  float* base = &hg[(size_t)cur * HDIM + lane * 4];
  atomicAdd(base + 0, a0); atomicAdd(base + 1, a1);
  atomicAdd(base + 2, a2); atomicAdd(base + 3, a3);
}

// cnt folded in via binary search on sorted gid (gid is L2-hot after k_readout).
__global__ __launch_bounds__(256) void k_div(const float* __restrict__ hg, const int* __restrict__ gid,
                                             float* __restrict__ out, int total, int N) {
  int i = blockIdx.x * 256 + threadIdx.x;
  if (i < total) {
    int g = i / HDIM;
    int lo = 0, hi = N;
    while (lo < hi) { int m = (lo + hi) >> 1; if (gid[m] < g) lo = m + 1; else hi = m; }
    int lb = lo;
    lo = 0; hi = N;
    while (lo < hi) { int m = (lo + hi) >> 1; if (gid[m] <= g) lo = m + 1; else hi = m; }
    int c = lo - lb;
    out[i] = hg[i] / (float)(c > 0 ? c : 1);
  }
}

// ---------------- launch ----------------
extern "C" void kernel_launch(void* const* d_in, const int* in_sizes, int n_in,
                              void* d_out, int out_size, void* d_ws, size_t ws_size,
                              hipStream_t stream) {
  (void)n_in; (void)ws_size; (void)out_size;
  const float* nodes_feat = (const float*)d_in[0];
  const float* W_emb = (const float*)d_in[4];
  const float* b_emb = (const float*)d_in[5];
  const float* pool_W = (const float*)d_in[6];
  const float* pool_b = (const float*)d_in[7];
  const float* app_W = (const float*)d_in[8];
  const float* app_b = (const float*)d_in[9];
  const int* src = (const int*)d_in[10];
  const int* dst = (const int*)d_in[11];
  const int* gid = (const int*)d_in[12];
  const int N = in_sizes[2];
  const int E = in_sizes[10];
  float* out = (float*)d_out;

  const int nb = (N + 127) >> 7;

  char* ws = (char*)d_ws;
  size_t off = 0;
  auto alloc = [&](size_t bytes) -> size_t {
    size_t o = off;
    off += (bytes + 1023) & ~size_t(1023);
    return o;
  };
  size_t o_gcur = alloc((size_t)MAXNB * 16 * 4);
  size_t o_hg   = alloc((size_t)G_GRAPHS * HDIM * 4);
  size_t zero_bytes = off;  // [gcur, hg]
  size_t o_ebuf = alloc((size_t)MAXNB * CAP * 4);     // packed src|ld<<20
  size_t o_h  = alloc((size_t)N * 112 * 2);
  size_t o_z  = alloc((size_t)N * 112);               // fp8 z
  size_t o_c  = alloc((size_t)N * 112 * 2);
  size_t o_we = alloc((size_t)112 * 64 * 2);
  size_t o_wp = alloc((size_t)2 * 112 * 128 * 2);
  size_t o_wa = alloc((size_t)2 * 112 * 224 * 2);

  int*           gcur = (int*)(ws + o_gcur);
  float*         hg   = (float*)(ws + o_hg);
  int*           ebuf = (int*)(ws + o_ebuf);
  _Float16*      h16  = (_Float16*)(ws + o_h);
  unsigned char* z8   = (unsigned char*)(ws + o_z);
  _Float16*      c16  = (_Float16*)(ws + o_c);
  _Float16*      wte  = (_Float16*)(ws + o_we);
  _Float16*      wtp  = (_Float16*)(ws + o_wp);
  _Float16*      wta  = (_Float16*)(ws + o_wa);

  (void)hipMemsetAsync(d_ws, 0, zero_bytes, stream);

  k_cvtall<<<(86016 + 255) / 256, 256, 0, stream>>>(W_emb, pool_W, app_W, wte, wtp, wta);

  k_scatter<<<(E + 16383) / 16384, 1024, 0, stream>>>(src, dst, gcur, ebuf, E, nb);

  const int nbMM = (N + 127) / 128;
  k_mmf<2, 0><<<nbMM, 256, 0, stream>>>(nodes_feat, nullptr, wte, b_emb, h16, N);

  for (int i = 0; i < 2; i++) {
    k_mmf<4, 1><<<nbMM, 256, 0, stream>>>(h16, nullptr, wtp + i * 112 * 128,
                                          pool_b + i * HDIM, z8, N);
    k_bagg<<<nb, 1024, 0, stream>>>(z8, ebuf, gcur, c16, N, nb);
    k_mmf<7, 2><<<nbMM, 256, 0, stream>>>(h16, c16, wta + i * 112 * 224,
                                          app_b + i * HDIM, h16, N);
  }

  k_readout<<<(N + 8 * 64 - 1) / (8 * 64), 256, 0, stream>>>(h16, gid, hg, N);
  k_div<<<(G_GRAPHS * HDIM + 255) / 256, 256, 0, stream>>>(hg, gid, out, G_GRAPHS * HDIM, N);
}